// Round 1
// baseline (9098.165 us; speedup 1.0000x reference)
//
#include <hip/hip_runtime.h>
#include <math.h>

// Problem constants
#define NG   12
#define Bb   8
#define Ss   1280
#define Cc   512
#define BS   10240            // B*S
#define SC   655360           // S*C per batch
#define OUT0 5242880          // B*S*C floats (output 0)

// ---------------------------------------------------------------------------
// pos precompute: cx, cy, r = cx*cx + cy*cy (numpy-style: mul, mul, add)
// ---------------------------------------------------------------------------
__global__ __launch_bounds__(256) void compute_pos(const float* __restrict__ box,
                                                   float4* __restrict__ posr) {
    int i = blockIdx.x * 256 + threadIdx.x;
    if (i < BS) {
        float x0 = box[i * 4 + 0], y0 = box[i * 4 + 1];
        float x1 = box[i * 4 + 2], y1 = box[i * 4 + 3];
        float cx = (x0 + x1) * 0.5f;
        float cy = (y0 + y1) * 0.5f;
        float px = __fmul_rn(cx, cx);
        float py = __fmul_rn(cy, cy);
        posr[i] = make_float4(cx, cy, __fadd_rn(px, py), 0.0f);
    }
}

// ---------------------------------------------------------------------------
// Generic f32 GEMM: C[M,N] = A[M,K] @ B[K,N] (+ bias[N]), optional batch via z
// 128x128 tile, BK=8, 256 threads, 8x8 per thread (split 4+4 strips).
// Grid: (N/128, M/128, batch)
// ---------------------------------------------------------------------------
__global__ __launch_bounds__(256) void gemm_nn(
    const float* __restrict__ A, const float* __restrict__ B,
    const float* __restrict__ bias, float* __restrict__ C,
    int K, int N, long long sA, long long sB, long long sC) {
    A += (long long)blockIdx.z * sA;
    B += (long long)blockIdx.z * sB;
    C += (long long)blockIdx.z * sC;

    const int tid = threadIdx.x;
    const int tx = tid & 15, ty = tid >> 4;
    const int tx4 = tx * 4, ty4 = ty * 4;
    const long long row0 = (long long)blockIdx.y * 128;
    const int col0 = blockIdx.x * 128;

    __shared__ float As[8][128];
    __shared__ float Bs[8][128];

    float acc[8][8];
    for (int i = 0; i < 8; ++i)
        for (int j = 0; j < 8; ++j) acc[i][j] = 0.0f;

    const int arow = tid >> 1;          // 0..127
    const int acol = (tid & 1) * 4;     // 0 or 4
    const int brow = tid >> 5;          // 0..7
    const int bcol = (tid & 31) * 4;    // 0..124

    const float* Ap = A + (row0 + arow) * (long long)K + acol;
    const float* Bp = B + (long long)brow * N + col0 + bcol;

    for (int k0 = 0; k0 < K; k0 += 8) {
        float4 av = *(const float4*)(Ap + k0);
        float4 bv = *(const float4*)(Bp + (long long)k0 * N);
        __syncthreads();
        As[acol + 0][arow] = av.x;
        As[acol + 1][arow] = av.y;
        As[acol + 2][arow] = av.z;
        As[acol + 3][arow] = av.w;
        *(float4*)&Bs[brow][bcol] = bv;
        __syncthreads();
#pragma unroll
        for (int kk = 0; kk < 8; ++kk) {
            float4 a0 = *(const float4*)&As[kk][ty4];
            float4 a1 = *(const float4*)&As[kk][ty4 + 64];
            float4 b0 = *(const float4*)&Bs[kk][tx4];
            float4 b1 = *(const float4*)&Bs[kk][tx4 + 64];
            float ar[8] = {a0.x, a0.y, a0.z, a0.w, a1.x, a1.y, a1.z, a1.w};
            float br[8] = {b0.x, b0.y, b0.z, b0.w, b1.x, b1.y, b1.z, b1.w};
#pragma unroll
            for (int i = 0; i < 8; ++i)
#pragma unroll
                for (int j = 0; j < 8; ++j)
                    acc[i][j] = fmaf(ar[i], br[j], acc[i][j]);
        }
    }

#pragma unroll
    for (int jh = 0; jh < 2; ++jh) {
        float4 bv = make_float4(0.f, 0.f, 0.f, 0.f);
        if (bias) bv = *(const float4*)&bias[col0 + jh * 64 + tx4];
#pragma unroll
        for (int ih = 0; ih < 2; ++ih) {
#pragma unroll
            for (int i = 0; i < 4; ++i) {
                long long r = row0 + ih * 64 + ty4 + i;
                float4 o;
                o.x = acc[ih * 4 + i][jh * 4 + 0] + bv.x;
                o.y = acc[ih * 4 + i][jh * 4 + 1] + bv.y;
                o.z = acc[ih * 4 + i][jh * 4 + 2] + bv.z;
                o.w = acc[ih * 4 + i][jh * 4 + 3] + bv.w;
                *(float4*)&C[r * N + col0 + jh * 64 + tx4] = o;
            }
        }
    }
}

// ---------------------------------------------------------------------------
// sim = theta @ phi^T * scale, masked (-inf where dist > thr). Batched over z.
// Grid: (10, 10, 8). M = N = 1280, K = 512.
// ---------------------------------------------------------------------------
__global__ __launch_bounds__(256) void gemm_nt_mask(
    const float* __restrict__ theta, const float* __restrict__ phi,
    const float4* __restrict__ posr, const int* __restrict__ OWp,
    float* __restrict__ simout, float scale) {
    const int b = blockIdx.z;
    const float* A = theta + (long long)b * Ss * Cc;
    const float* Bq = phi + (long long)b * Ss * Cc;
    float* C = simout + (long long)b * Ss * Ss;
    const float4* pr = posr + b * Ss;
    const float thr = 0.2f * (float)(*OWp);

    const int tid = threadIdx.x;
    const int tx = tid & 15, ty = tid >> 4;
    const int tx4 = tx * 4, ty4 = ty * 4;
    const int row0 = blockIdx.y * 128;
    const int col0 = blockIdx.x * 128;

    __shared__ float As[8][128];
    __shared__ float Bs[8][128];

    float acc[8][8];
    for (int i = 0; i < 8; ++i)
        for (int j = 0; j < 8; ++j) acc[i][j] = 0.0f;

    const int lrow = tid >> 1;
    const int lcol = (tid & 1) * 4;
    const float* Ap = A + (long long)(row0 + lrow) * Cc + lcol;
    const float* Bp = Bq + (long long)(col0 + lrow) * Cc + lcol;

    for (int k0 = 0; k0 < Cc; k0 += 8) {
        float4 av = *(const float4*)(Ap + k0);
        float4 bv = *(const float4*)(Bp + k0);
        __syncthreads();
        As[lcol + 0][lrow] = av.x;
        As[lcol + 1][lrow] = av.y;
        As[lcol + 2][lrow] = av.z;
        As[lcol + 3][lrow] = av.w;
        Bs[lcol + 0][lrow] = bv.x;
        Bs[lcol + 1][lrow] = bv.y;
        Bs[lcol + 2][lrow] = bv.z;
        Bs[lcol + 3][lrow] = bv.w;
        __syncthreads();
#pragma unroll
        for (int kk = 0; kk < 8; ++kk) {
            float4 a0 = *(const float4*)&As[kk][ty4];
            float4 a1 = *(const float4*)&As[kk][ty4 + 64];
            float4 b0 = *(const float4*)&Bs[kk][tx4];
            float4 b1 = *(const float4*)&Bs[kk][tx4 + 64];
            float ar[8] = {a0.x, a0.y, a0.z, a0.w, a1.x, a1.y, a1.z, a1.w};
            float br[8] = {b0.x, b0.y, b0.z, b0.w, b1.x, b1.y, b1.z, b1.w};
#pragma unroll
            for (int i = 0; i < 8; ++i)
#pragma unroll
                for (int j = 0; j < 8; ++j)
                    acc[i][j] = fmaf(ar[i], br[j], acc[i][j]);
        }
    }

    float4 pn[2][4], pm[2][4];
#pragma unroll
    for (int ih = 0; ih < 2; ++ih)
#pragma unroll
        for (int i = 0; i < 4; ++i) pn[ih][i] = pr[row0 + ih * 64 + ty4 + i];
#pragma unroll
    for (int jh = 0; jh < 2; ++jh)
#pragma unroll
        for (int j = 0; j < 4; ++j) pm[jh][j] = pr[col0 + jh * 64 + tx4 + j];

#pragma unroll
    for (int ih = 0; ih < 2; ++ih) {
#pragma unroll
        for (int i = 0; i < 4; ++i) {
            int r = row0 + ih * 64 + ty4 + i;
#pragma unroll
            for (int jh = 0; jh < 2; ++jh) {
                float o[4];
#pragma unroll
                for (int j = 0; j < 4; ++j) {
                    // e like a K=2 BLAS dot: mul then fma
                    float e = fmaf(pn[ih][i].y, pm[jh][j].y, pn[ih][i].x * pm[jh][j].x);
                    float d2 = __fadd_rn(__fsub_rn(pn[ih][i].z, __fmul_rn(2.0f, e)), pm[jh][j].z);
                    float dist = sqrtf(fmaxf(d2, 0.0f));
                    float v = acc[ih * 4 + i][jh * 4 + j] * scale;
                    o[j] = (dist > thr) ? -INFINITY : v;
                }
                float4 ov = make_float4(o[0], o[1], o[2], o[3]);
                *(float4*)&C[(long long)r * Ss + col0 + jh * 64 + tx4] = ov;
            }
        }
    }
}

// ---------------------------------------------------------------------------
// Row softmax in-place over rows of length 1280. One block (256 thr) per row.
// ---------------------------------------------------------------------------
__global__ __launch_bounds__(256) void softmax_rows(float* __restrict__ sim) {
    const int row = blockIdx.x;
    float* p = sim + (long long)row * Ss;
    __shared__ float buf[Ss];
    __shared__ float wred[4];
    const int t = threadIdx.x;

    float m = -INFINITY;
    for (int j = t; j < Ss; j += 256) {
        float v = p[j];
        buf[j] = v;
        m = fmaxf(m, v);
    }
#pragma unroll
    for (int o = 32; o > 0; o >>= 1) m = fmaxf(m, __shfl_down(m, o));
    if ((t & 63) == 0) wred[t >> 6] = m;
    __syncthreads();
    const float m4 = fmaxf(fmaxf(wred[0], wred[1]), fmaxf(wred[2], wred[3]));
    __syncthreads();

    float s = 0.0f;
    for (int j = t; j < Ss; j += 256) {
        float e = expf(buf[j] - m4);
        buf[j] = e;
        s += e;
    }
#pragma unroll
    for (int o = 32; o > 0; o >>= 1) s += __shfl_down(s, o);
    if ((t & 63) == 0) wred[t >> 6] = s;
    __syncthreads();
    const float total = wred[0] + wred[1] + wred[2] + wred[3];
    const float inv = 1.0f / total;
    for (int j = t; j < Ss; j += 256) p[j] = buf[j] * inv;
}

// ---------------------------------------------------------------------------
// LayerNorm reductions (two-stage, deterministic)
// ---------------------------------------------------------------------------
__global__ __launch_bounds__(256) void reduce1(const float* __restrict__ agg,
                                               float2* __restrict__ part) {
    const int b = blockIdx.y;
    const float4* p = (const float4*)(agg + (long long)b * SC);
    float s = 0.f, ss = 0.f;
    for (int j = blockIdx.x * 256 + threadIdx.x; j < SC / 4; j += 64 * 256) {
        float4 v = p[j];
        s += v.x + v.y + v.z + v.w;
        ss += v.x * v.x + v.y * v.y + v.z * v.z + v.w * v.w;
    }
#pragma unroll
    for (int o = 32; o > 0; o >>= 1) {
        s += __shfl_down(s, o);
        ss += __shfl_down(ss, o);
    }
    __shared__ float2 wred[4];
    if ((threadIdx.x & 63) == 0) wred[threadIdx.x >> 6] = make_float2(s, ss);
    __syncthreads();
    if (threadIdx.x == 0) {
        float S = wred[0].x + wred[1].x + wred[2].x + wred[3].x;
        float SS = wred[0].y + wred[1].y + wred[2].y + wred[3].y;
        part[b * 64 + blockIdx.x] = make_float2(S, SS);
    }
}

__global__ void reduce2(const float2* __restrict__ part, float2* __restrict__ stats) {
    const int b = blockIdx.x;
    float2 v = part[b * 64 + threadIdx.x];
    float s = v.x, ss = v.y;
#pragma unroll
    for (int o = 32; o > 0; o >>= 1) {
        s += __shfl_down(s, o);
        ss += __shfl_down(ss, o);
    }
    if (threadIdx.x == 0) {
        const float invn = 1.0f / (float)SC;
        float mu = s * invn;
        float var = ss * invn - mu * mu;
        stats[b] = make_float2(mu, 1.0f / sqrtf(var + 1e-5f));
    }
}

// ---------------------------------------------------------------------------
// normed = (agg - mu) * rstd * ln_scale + ln_bias; out (+)= relu(normed)
// ---------------------------------------------------------------------------
__global__ __launch_bounds__(256) void ln_relu_acc(
    const float* __restrict__ agg, const float2* __restrict__ stats,
    const float* __restrict__ lnsc, const float* __restrict__ lnbi,
    float* __restrict__ out, int first) {
    for (int idx = blockIdx.x * 256 + threadIdx.x; idx < (Bb * SC) / 4;
         idx += gridDim.x * 256) {
        int b = idx / (SC / 4);
        int j = idx - b * (SC / 4);
        float2 st = stats[b];
        float4 a = ((const float4*)agg)[idx];
        float4 sc = ((const float4*)lnsc)[j];
        float4 bi = ((const float4*)lnbi)[j];
        float4 o;
        o.x = fmaxf((a.x - st.x) * st.y * sc.x + bi.x, 0.f);
        o.y = fmaxf((a.y - st.x) * st.y * sc.y + bi.y, 0.f);
        o.z = fmaxf((a.z - st.x) * st.y * sc.z + bi.z, 0.f);
        o.w = fmaxf((a.w - st.x) * st.y * sc.w + bi.w, 0.f);
        float4* op = (float4*)out + idx;
        if (!first) {
            float4 pv = *op;
            o.x += pv.x; o.y += pv.y; o.z += pv.z; o.w += pv.w;
        }
        *op = o;
    }
}

// ---------------------------------------------------------------------------
extern "C" void kernel_launch(void* const* d_in, const int* in_sizes, int n_in,
                              void* d_out, int out_size, void* d_ws, size_t ws_size,
                              hipStream_t stream) {
    const float* x        = (const float*)d_in[0];
    const float* box      = (const float*)d_in[1];
    const float* W_theta  = (const float*)d_in[2];
    const float* b_theta  = (const float*)d_in[3];
    const float* W_phi    = (const float*)d_in[4];
    const float* b_phi    = (const float*)d_in[5];
    const float* W_gcn    = (const float*)d_in[6];
    const float* ln_scale = (const float*)d_in[7];
    const float* ln_bias  = (const float*)d_in[8];
    const int*   OWp      = (const int*)d_in[10];

    float* out = (float*)d_out;            // [8,1280,512]
    float* relation = out + OUT0;          // [8,1280,1280] (output 1 region)

    char* ws = (char*)d_ws;
    float4* posr = (float4*)ws;                        // 10240 * 16 B
    float*  buf1 = (float*)(ws + BS * 16);             // theta -> agg1
    float*  buf2 = buf1 + OUT0;                        // phi   -> agg
    float2* part = (float2*)(buf2 + OUT0);             // 8*64 float2
    float2* stats = part + Bb * 64;                    // 8 float2

    compute_pos<<<dim3((BS + 255) / 256), dim3(256), 0, stream>>>(box, posr);

    const float inv_sqrt = 0.044194173824159216f;  // 1/sqrt(512)

    for (int i = 0; i < NG; ++i) {
        const long long wo = (long long)i * Cc * Cc;
        // theta = x @ W_theta[i] + b_theta[i]
        gemm_nn<<<dim3(4, 80, 1), dim3(256), 0, stream>>>(
            x, W_theta + wo, b_theta + i * Cc, buf1, Cc, Cc, 0, 0, 0);
        // phi = x @ W_phi[i] + b_phi[i]
        gemm_nn<<<dim3(4, 80, 1), dim3(256), 0, stream>>>(
            x, W_phi + wo, b_phi + i * Cc, buf2, Cc, Cc, 0, 0, 0);
        // sim (masked, scaled) -> relation region of d_out
        gemm_nt_mask<<<dim3(10, 10, 8), dim3(256), 0, stream>>>(
            buf1, buf2, posr, OWp, relation, inv_sqrt);
        // softmax rows in place
        softmax_rows<<<dim3(Bb * Ss), dim3(256), 0, stream>>>(relation);
        // agg1 = relation @ x   (batched)
        gemm_nn<<<dim3(4, 10, 8), dim3(256), 0, stream>>>(
            relation, x, nullptr, buf1, Ss, Cc,
            (long long)Ss * Ss, (long long)SC, (long long)SC);
        // agg = agg1 @ W_gcn[i]
        gemm_nn<<<dim3(4, 80, 1), dim3(256), 0, stream>>>(
            buf1, W_gcn + wo, nullptr, buf2, Cc, Cc, 0, 0, 0);
        // LayerNorm stats over [S, C] per batch
        reduce1<<<dim3(64, 8), dim3(256), 0, stream>>>(buf2, part);
        reduce2<<<dim3(8), dim3(64), 0, stream>>>(part, stats);
        // out (+)= relu(LN(agg))
        ln_relu_acc<<<dim3(2048), dim3(256), 0, stream>>>(
            buf2, stats, ln_scale + (long long)i * SC, ln_bias + (long long)i * SC,
            out, i == 0 ? 1 : 0);
    }
}

// Round 2
// 2209.777 us; speedup vs baseline: 4.1172x; 4.1172x over previous
//
#include <hip/hip_runtime.h>
#include <math.h>

// Problem constants
#define NG   12
#define Bb   8
#define Ss   1280
#define Cc   512
#define BS   10240            // B*S
#define SC   655360           // S*C per batch
#define OUT0 5242880          // B*S*C floats (output 0)

typedef __bf16 bf16x8 __attribute__((ext_vector_type(8)));
typedef __bf16 bf16x4v __attribute__((ext_vector_type(4)));
typedef float  f32x4  __attribute__((ext_vector_type(4)));

#define GLOAD16(gp, lp)                                                        \
    __builtin_amdgcn_global_load_lds(                                          \
        (const __attribute__((address_space(1))) void*)(gp),                   \
        (__attribute__((address_space(3))) void*)(lp), 16, 0, 0)

// ---------------------------------------------------------------------------
// pos precompute: cx, cy, r = cx*cx + cy*cy
// ---------------------------------------------------------------------------
__global__ __launch_bounds__(256) void compute_pos(const float* __restrict__ box,
                                                   float4* __restrict__ posr) {
    int i = blockIdx.x * 256 + threadIdx.x;
    if (i < BS) {
        float x0 = box[i * 4 + 0], y0 = box[i * 4 + 1];
        float x1 = box[i * 4 + 2], y1 = box[i * 4 + 3];
        float cx = (x0 + x1) * 0.5f;
        float cy = (y0 + y1) * 0.5f;
        float px = __fmul_rn(cx, cx);
        float py = __fmul_rn(cy, cy);
        posr[i] = make_float4(cx, cy, __fadd_rn(px, py), 0.0f);
    }
}

// ---------------------------------------------------------------------------
// f32 -> bf16 elementwise convert (vectorized)
// ---------------------------------------------------------------------------
__global__ __launch_bounds__(256) void cvt_bf16(const float* __restrict__ src,
                                                __bf16* __restrict__ dst, int n4) {
    for (int i = blockIdx.x * 256 + threadIdx.x; i < n4; i += gridDim.x * 256) {
        float4 v = ((const float4*)src)[i];
        bf16x4v o;
        o[0] = (__bf16)v.x; o[1] = (__bf16)v.y; o[2] = (__bf16)v.z; o[3] = (__bf16)v.w;
        *(bf16x4v*)(dst + i * 4) = o;
    }
}

// ---------------------------------------------------------------------------
// Tiled transpose + convert: dst[c][r] (bf16) = src[r][c] (f32). 64x64 tiles.
// grid: (Rtiles, Ctiles, batch)
// ---------------------------------------------------------------------------
__global__ __launch_bounds__(256) void transpose_cvt(
    const float* __restrict__ src, __bf16* __restrict__ dst,
    int ldsrc, int lddst, long long sSrc, long long sDst) {
    src += sSrc * blockIdx.z;
    dst += sDst * blockIdx.z;
    __shared__ float tile[64][65];
    const int t = threadIdx.x, tx = t & 15, ty = t >> 4;
    const int r0 = blockIdx.x * 64, c0 = blockIdx.y * 64;
#pragma unroll
    for (int rr = 0; rr < 4; ++rr) {
        int r = ty + rr * 16;
        float4 v = *(const float4*)(src + (long long)(r0 + r) * ldsrc + c0 + tx * 4);
        tile[r][tx * 4 + 0] = v.x;
        tile[r][tx * 4 + 1] = v.y;
        tile[r][tx * 4 + 2] = v.z;
        tile[r][tx * 4 + 3] = v.w;
    }
    __syncthreads();
#pragma unroll
    for (int rr = 0; rr < 4; ++rr) {
        int c = ty + rr * 16;   // dst row = source col c0+c
        bf16x4v o;
        o[0] = (__bf16)tile[tx * 4 + 0][c];
        o[1] = (__bf16)tile[tx * 4 + 1][c];
        o[2] = (__bf16)tile[tx * 4 + 2][c];
        o[3] = (__bf16)tile[tx * 4 + 3][c];
        *(bf16x4v*)(dst + (long long)(c0 + c) * lddst + r0 + tx * 4) = o;
    }
}

// ---------------------------------------------------------------------------
// bf16 MFMA GEMM, "nt" layout: C[M][N] = A[M][K] * Bt[N][K]^T  (f32 accum)
// 128x128 tile, BK=32, 256 threads (4 waves, 2x2), 4x4 16x16 frags per wave.
// MODE 0: +bias(theta/phi concat), bf16 out      (theta/phi)
// MODE 1: *scale, position mask -> -inf, f32 out (sim)
// MODE 2: bf16 out                               (agg1 = P @ x)
// MODE 3: f32 out                                (agg = agg1 @ Wg)
// grid: (N/128, M/128, batch)
// ---------------------------------------------------------------------------
template <int MODE>
__global__ __launch_bounds__(256) void gemm_bf16(
    const __bf16* __restrict__ A, const __bf16* __restrict__ Bt, void* __restrict__ Cv,
    int lda, int ldb, int ldc, int K,
    long long sA, long long sB, long long sC,
    const float* __restrict__ bias_th, const float* __restrict__ bias_ph,
    const float4* __restrict__ posr, const int* __restrict__ OWp, float scale) {
    const int bz = blockIdx.z;
    A += sA * bz;
    Bt += sB * bz;
    const int m0 = blockIdx.y * 128, n0 = blockIdx.x * 128;

    __shared__ char lds[16384];  // A tile [128][32] bf16 @0, B tile @8192

    const int t = threadIdx.x, l = t & 63, w = t >> 6;
    const int wm = w >> 1, wn = w & 1;

    f32x4 acc[4][4] = {};

    // staging geometry: per wave 2 A-instrs + 2 B-instrs of 1 KiB each
    const int beta0 = w * 2048 + (l << 4);
    const int beta1 = beta0 + 1024;
    const int ar0 = beta0 >> 6, akb0 = beta0 & 63;
    const int ar1 = beta1 >> 6, akb1 = beta1 & 63;
    const char* Abase = (const char*)A + (long long)m0 * lda * 2;
    const char* Bbase = (const char*)Bt + (long long)n0 * ldb * 2;
    char* ldsA = lds + w * 2048;          // wave-uniform dest base
    char* ldsB = lds + 8192 + w * 2048;

    const int fr = (l & 15);        // fragment row/col within 16
    const int g16 = (l >> 4) * 16;  // 16-byte k-group offset

    for (int k0 = 0; k0 < K; k0 += 32) {
        const char* Ak = Abase + (long long)k0 * 2;
        const char* Bk = Bbase + (long long)k0 * 2;
        GLOAD16(Ak + (long long)ar0 * lda * 2 + akb0, ldsA);
        GLOAD16(Ak + (long long)ar1 * lda * 2 + akb1, ldsA + 1024);
        GLOAD16(Bk + (long long)ar0 * ldb * 2 + akb0, ldsB);
        GLOAD16(Bk + (long long)ar1 * ldb * 2 + akb1, ldsB + 1024);
        __syncthreads();
        bf16x8 af[4], bf[4];
#pragma unroll
        for (int i = 0; i < 4; ++i)
            af[i] = *(const bf16x8*)(lds + (wm * 64 + i * 16 + fr) * 64 + g16);
#pragma unroll
        for (int j = 0; j < 4; ++j)
            bf[j] = *(const bf16x8*)(lds + 8192 + (wn * 64 + j * 16 + fr) * 64 + g16);
#pragma unroll
        for (int i = 0; i < 4; ++i)
#pragma unroll
            for (int j = 0; j < 4; ++j)
                acc[i][j] = __builtin_amdgcn_mfma_f32_16x16x32_bf16(af[i], bf[j],
                                                                    acc[i][j], 0, 0, 0);
        __syncthreads();
    }

    // Epilogue. C/D frag: col = n0+wn*64+j*16+(l&15), row = m0+wm*64+i*16+(l>>4)*4+r
    const int crow0 = m0 + wm * 64 + (l >> 4) * 4;
    const int ccol0 = n0 + wn * 64 + fr;

    if (MODE == 0) {
        __bf16* C = (__bf16*)Cv;
#pragma unroll
        for (int j = 0; j < 4; ++j) {
            int col = ccol0 + j * 16;
            float bv = (col < Cc) ? bias_th[col] : bias_ph[col - Cc];
#pragma unroll
            for (int i = 0; i < 4; ++i)
#pragma unroll
                for (int r = 0; r < 4; ++r) {
                    int row = crow0 + i * 16 + r;
                    C[(long long)row * ldc + col] = (__bf16)(acc[i][j][r] + bv);
                }
        }
    } else if (MODE == 1) {
        float* C = (float*)Cv + sC * bz;
        const float4* pr = posr + bz * Ss;
        const float thr = 0.2f * (float)(*OWp);
        float4 pm[4];
#pragma unroll
        for (int j = 0; j < 4; ++j) pm[j] = pr[ccol0 + j * 16];
#pragma unroll
        for (int i = 0; i < 4; ++i)
#pragma unroll
            for (int r = 0; r < 4; ++r) {
                int row = crow0 + i * 16 + r;
                float4 pn = pr[row];
#pragma unroll
                for (int j = 0; j < 4; ++j) {
                    float e = fmaf(pn.y, pm[j].y, pn.x * pm[j].x);
                    float d2 = __fadd_rn(__fsub_rn(pn.z, __fmul_rn(2.0f, e)), pm[j].z);
                    float dist = sqrtf(fmaxf(d2, 0.0f));
                    float v = acc[i][j][r] * scale;
                    C[(long long)row * ldc + ccol0 + j * 16] =
                        (dist > thr) ? -INFINITY : v;
                }
            }
    } else if (MODE == 2) {
        __bf16* C = (__bf16*)Cv + sC * bz;
#pragma unroll
        for (int j = 0; j < 4; ++j)
#pragma unroll
            for (int i = 0; i < 4; ++i)
#pragma unroll
                for (int r = 0; r < 4; ++r) {
                    int row = crow0 + i * 16 + r;
                    C[(long long)row * ldc + ccol0 + j * 16] = (__bf16)acc[i][j][r];
                }
    } else {
        float* C = (float*)Cv + sC * bz;
#pragma unroll
        for (int j = 0; j < 4; ++j)
#pragma unroll
            for (int i = 0; i < 4; ++i)
#pragma unroll
                for (int r = 0; r < 4; ++r) {
                    int row = crow0 + i * 16 + r;
                    C[(long long)row * ldc + ccol0 + j * 16] = acc[i][j][r];
                }
    }
}

// ---------------------------------------------------------------------------
// Row softmax over rows of length 1280 (f32 in). Writes bf16 always; f32 back
// in place when write_f32 (last graph -> relation output).
// ---------------------------------------------------------------------------
__global__ __launch_bounds__(256) void softmax_rows(
    float* __restrict__ sim, __bf16* __restrict__ relbf, int write_f32) {
    const int row = blockIdx.x;
    float* p = sim + (long long)row * Ss;
    __bf16* q = relbf + (long long)row * Ss;
    __shared__ float buf[Ss];
    __shared__ float wred[4];
    const int t = threadIdx.x;

    float m = -INFINITY;
    for (int j = t; j < Ss; j += 256) {
        float v = p[j];
        buf[j] = v;
        m = fmaxf(m, v);
    }
#pragma unroll
    for (int o = 32; o > 0; o >>= 1) m = fmaxf(m, __shfl_down(m, o));
    if ((t & 63) == 0) wred[t >> 6] = m;
    __syncthreads();
    const float m4 = fmaxf(fmaxf(wred[0], wred[1]), fmaxf(wred[2], wred[3]));
    __syncthreads();

    float s = 0.0f;
    for (int j = t; j < Ss; j += 256) {
        float e = expf(buf[j] - m4);
        buf[j] = e;
        s += e;
    }
#pragma unroll
    for (int o = 32; o > 0; o >>= 1) s += __shfl_down(s, o);
    if ((t & 63) == 0) wred[t >> 6] = s;
    __syncthreads();
    const float total = wred[0] + wred[1] + wred[2] + wred[3];
    const float inv = 1.0f / total;
    for (int j = t; j < Ss; j += 256) {
        float v = buf[j] * inv;
        q[j] = (__bf16)v;
        if (write_f32) p[j] = v;
    }
}

// ---------------------------------------------------------------------------
// LayerNorm reductions (two-stage, deterministic)
// ---------------------------------------------------------------------------
__global__ __launch_bounds__(256) void reduce1(const float* __restrict__ agg,
                                               float2* __restrict__ part) {
    const int b = blockIdx.y;
    const float4* p = (const float4*)(agg + (long long)b * SC);
    float s = 0.f, ss = 0.f;
    for (int j = blockIdx.x * 256 + threadIdx.x; j < SC / 4; j += 64 * 256) {
        float4 v = p[j];
        s += v.x + v.y + v.z + v.w;
        ss += v.x * v.x + v.y * v.y + v.z * v.z + v.w * v.w;
    }
#pragma unroll
    for (int o = 32; o > 0; o >>= 1) {
        s += __shfl_down(s, o);
        ss += __shfl_down(ss, o);
    }
    __shared__ float2 wred[4];
    if ((threadIdx.x & 63) == 0) wred[threadIdx.x >> 6] = make_float2(s, ss);
    __syncthreads();
    if (threadIdx.x == 0) {
        float S = wred[0].x + wred[1].x + wred[2].x + wred[3].x;
        float SS = wred[0].y + wred[1].y + wred[2].y + wred[3].y;
        part[b * 64 + blockIdx.x] = make_float2(S, SS);
    }
}

__global__ void reduce2(const float2* __restrict__ part, float2* __restrict__ stats) {
    const int b = blockIdx.x;
    float2 v = part[b * 64 + threadIdx.x];
    float s = v.x, ss = v.y;
#pragma unroll
    for (int o = 32; o > 0; o >>= 1) {
        s += __shfl_down(s, o);
        ss += __shfl_down(ss, o);
    }
    if (threadIdx.x == 0) {
        const float invn = 1.0f / (float)SC;
        float mu = s * invn;
        float var = ss * invn - mu * mu;
        stats[b] = make_float2(mu, 1.0f / sqrtf(var + 1e-5f));
    }
}

// ---------------------------------------------------------------------------
// out (+)= relu((agg - mu) * rstd * ln_scale + ln_bias)
// ---------------------------------------------------------------------------
__global__ __launch_bounds__(256) void ln_relu_acc(
    const float* __restrict__ agg, const float2* __restrict__ stats,
    const float* __restrict__ lnsc, const float* __restrict__ lnbi,
    float* __restrict__ out, int first) {
    for (int idx = blockIdx.x * 256 + threadIdx.x; idx < (Bb * SC) / 4;
         idx += gridDim.x * 256) {
        int b = idx / (SC / 4);
        int j = idx - b * (SC / 4);
        float2 st = stats[b];
        float4 a = ((const float4*)agg)[idx];
        float4 sc = ((const float4*)lnsc)[j];
        float4 bi = ((const float4*)lnbi)[j];
        float4 o;
        o.x = fmaxf((a.x - st.x) * st.y * sc.x + bi.x, 0.f);
        o.y = fmaxf((a.y - st.x) * st.y * sc.y + bi.y, 0.f);
        o.z = fmaxf((a.z - st.x) * st.y * sc.z + bi.z, 0.f);
        o.w = fmaxf((a.w - st.x) * st.y * sc.w + bi.w, 0.f);
        float4* op = (float4*)out + idx;
        if (!first) {
            float4 pv = *op;
            o.x += pv.x; o.y += pv.y; o.z += pv.z; o.w += pv.w;
        }
        *op = o;
    }
}

// ---------------------------------------------------------------------------
extern "C" void kernel_launch(void* const* d_in, const int* in_sizes, int n_in,
                              void* d_out, int out_size, void* d_ws, size_t ws_size,
                              hipStream_t stream) {
    const float* x        = (const float*)d_in[0];
    const float* box      = (const float*)d_in[1];
    const float* W_theta  = (const float*)d_in[2];
    const float* b_theta  = (const float*)d_in[3];
    const float* W_phi    = (const float*)d_in[4];
    const float* b_phi    = (const float*)d_in[5];
    const float* W_gcn    = (const float*)d_in[6];
    const float* ln_scale = (const float*)d_in[7];
    const float* ln_bias  = (const float*)d_in[8];
    const int*   OWp      = (const int*)d_in[10];

    float* out = (float*)d_out;            // [8,1280,512]
    float* rel_f32 = out + OUT0;           // [8,1280,1280] (output 1 region)

    char* ws = (char*)d_ws;
    float4* posr  = (float4*)(ws + 0);                  //   163840 B
    __bf16* x_bf  = (__bf16*)(ws + 163840);             // 10485760 B [10240][512]
    __bf16* x_t   = (__bf16*)(ws + 10649600);           // 10485760 B [8][512][1280]
    __bf16* Wtp   = (__bf16*)(ws + 21135360);           // 12582912 B [12][1024][512]
    __bf16* Wg    = (__bf16*)(ws + 33718272);           //  6291456 B [12][512][512]
    __bf16* thph  = (__bf16*)(ws + 40009728);           // 20971520 B [10240][1024]
    float*  aggF  = (float*)(ws + 40009728);            // alias: [10240][512] f32
    __bf16* relbf = (__bf16*)(ws + 60981248);           // 26214400 B [8][1280][1280]
    __bf16* agg1  = (__bf16*)(ws + 87195648);           // 10485760 B [10240][512]
    float2* part  = (float2*)(ws + 97681408);
    float2* stats = part + Bb * 64;

    // ---- one-time prep ----
    compute_pos<<<dim3(40), dim3(256), 0, stream>>>(box, posr);
    cvt_bf16<<<dim3(2048), dim3(256), 0, stream>>>(x, x_bf, OUT0 / 4);
    // x_t[b][c][s] = x[b][s][c]
    transpose_cvt<<<dim3(20, 8, 8), dim3(256), 0, stream>>>(
        x, x_t, Cc, Ss, (long long)SC, (long long)SC);
    // Wtp[i][f][c] = W_theta[i][c][f] (rows 0..511), W_phi (rows 512..1023)
    transpose_cvt<<<dim3(8, 8, 12), dim3(256), 0, stream>>>(
        W_theta, Wtp, Cc, Cc, (long long)Cc * Cc, (long long)1024 * Cc);
    transpose_cvt<<<dim3(8, 8, 12), dim3(256), 0, stream>>>(
        W_phi, Wtp + (long long)Cc * Cc, Cc, Cc, (long long)Cc * Cc, (long long)1024 * Cc);
    transpose_cvt<<<dim3(8, 8, 12), dim3(256), 0, stream>>>(
        W_gcn, Wg, Cc, Cc, (long long)Cc * Cc, (long long)Cc * Cc);

    const float inv_sqrt = 0.044194173824159216f;  // 1/sqrt(512)

    for (int i = 0; i < NG; ++i) {
        const __bf16* Wtp_i = Wtp + (long long)i * 1024 * Cc;
        const __bf16* Wg_i  = Wg + (long long)i * Cc * Cc;
        // theta|phi = x @ [W_theta; W_phi] + bias  -> thph [10240][1024] bf16
        gemm_bf16<0><<<dim3(8, 80, 1), dim3(256), 0, stream>>>(
            x_bf, Wtp_i, thph, Cc, Cc, 1024, Cc, 0, 0, 0,
            b_theta + i * Cc, b_phi + i * Cc, nullptr, nullptr, 0.f);
        // sim = theta @ phi^T * scale, masked -> rel_f32 (out region)
        gemm_bf16<1><<<dim3(10, 10, 8), dim3(256), 0, stream>>>(
            thph, thph + Cc, rel_f32, 1024, 1024, Ss, Cc,
            (long long)Ss * 1024, (long long)Ss * 1024, (long long)Ss * Ss,
            nullptr, nullptr, posr, OWp, inv_sqrt);
        // softmax rows; bf16 out always, f32 in-place on last graph
        softmax_rows<<<dim3(BS), dim3(256), 0, stream>>>(rel_f32, relbf,
                                                         i == NG - 1 ? 1 : 0);
        // agg1 = relation @ x  -> bf16 [10240][512]
        gemm_bf16<2><<<dim3(4, 10, 8), dim3(256), 0, stream>>>(
            relbf, x_t, agg1, Ss, Ss, Cc, Ss,
            (long long)Ss * Ss, (long long)Cc * Ss, (long long)Ss * Cc,
            nullptr, nullptr, nullptr, nullptr, 0.f);
        // agg = agg1 @ W_gcn -> f32 (aliases thph buffer)
        gemm_bf16<3><<<dim3(4, 80, 1), dim3(256), 0, stream>>>(
            agg1, Wg_i, aggF, Cc, Cc, Cc, Cc, 0, 0, 0,
            nullptr, nullptr, nullptr, nullptr, 0.f);
        // LayerNorm over [S, C] per batch + relu + accumulate
        reduce1<<<dim3(64, 8), dim3(256), 0, stream>>>(aggF, part);
        reduce2<<<dim3(8), dim3(64), 0, stream>>>(part, stats);
        ln_relu_acc<<<dim3(2048), dim3(256), 0, stream>>>(
            aggF, stats, ln_scale + (long long)i * SC, ln_bias + (long long)i * SC,
            out, i == 0 ? 1 : 0);
    }
}

// Round 5
// 1948.806 us; speedup vs baseline: 4.6686x; 1.1339x over previous
//
#include <hip/hip_runtime.h>
#include <math.h>

// Problem constants
#define NG   12
#define Bb   8
#define Ss   1280
#define Cc   512
#define BS   10240            // B*S
#define SC   655360           // S*C per batch
#define OUT0 5242880          // B*S*C floats (output 0)

typedef __bf16 bf16x8 __attribute__((ext_vector_type(8)));
typedef __bf16 bf16x4v __attribute__((ext_vector_type(4)));
typedef float  f32x4  __attribute__((ext_vector_type(4)));

#define GLOAD16(gp, lp)                                                        \
    __builtin_amdgcn_global_load_lds(                                          \
        (const __attribute__((address_space(1))) void*)(gp),                   \
        (__attribute__((address_space(3))) void*)(lp), 16, 0, 0)

// ---------------------------------------------------------------------------
// pos precompute: cx, cy, r = cx*cx + cy*cy
// ---------------------------------------------------------------------------
__global__ __launch_bounds__(256) void compute_pos(const float* __restrict__ box,
                                                   float4* __restrict__ posr) {
    int i = blockIdx.x * 256 + threadIdx.x;
    if (i < BS) {
        float x0 = box[i * 4 + 0], y0 = box[i * 4 + 1];
        float x1 = box[i * 4 + 2], y1 = box[i * 4 + 3];
        float cx = (x0 + x1) * 0.5f;
        float cy = (y0 + y1) * 0.5f;
        float px = __fmul_rn(cx, cx);
        float py = __fmul_rn(cy, cy);
        posr[i] = make_float4(cx, cy, __fadd_rn(px, py), 0.0f);
    }
}

// ---------------------------------------------------------------------------
// f32 -> bf16 elementwise convert (vectorized)
// ---------------------------------------------------------------------------
__global__ __launch_bounds__(256) void cvt_bf16(const float* __restrict__ src,
                                                __bf16* __restrict__ dst, int n4) {
    for (int i = blockIdx.x * 256 + threadIdx.x; i < n4; i += gridDim.x * 256) {
        float4 v = ((const float4*)src)[i];
        bf16x4v o;
        o[0] = (__bf16)v.x; o[1] = (__bf16)v.y; o[2] = (__bf16)v.z; o[3] = (__bf16)v.w;
        *(bf16x4v*)(dst + i * 4) = o;
    }
}

// ---------------------------------------------------------------------------
// Tiled transpose + convert: dst[c][r] (bf16) = src[r][c] (f32). 64x64 tiles.
// ---------------------------------------------------------------------------
__global__ __launch_bounds__(256) void transpose_cvt(
    const float* __restrict__ src, __bf16* __restrict__ dst,
    int ldsrc, int lddst, long long sSrc, long long sDst) {
    src += sSrc * blockIdx.z;
    dst += sDst * blockIdx.z;
    __shared__ float tile[64][65];
    const int t = threadIdx.x, tx = t & 15, ty = t >> 4;
    const int r0 = blockIdx.x * 64, c0 = blockIdx.y * 64;
#pragma unroll
    for (int rr = 0; rr < 4; ++rr) {
        int r = ty + rr * 16;
        float4 v = *(const float4*)(src + (long long)(r0 + r) * ldsrc + c0 + tx * 4);
        tile[r][tx * 4 + 0] = v.x;
        tile[r][tx * 4 + 1] = v.y;
        tile[r][tx * 4 + 2] = v.z;
        tile[r][tx * 4 + 3] = v.w;
    }
    __syncthreads();
#pragma unroll
    for (int rr = 0; rr < 4; ++rr) {
        int c = ty + rr * 16;
        bf16x4v o;
        o[0] = (__bf16)tile[tx * 4 + 0][c];
        o[1] = (__bf16)tile[tx * 4 + 1][c];
        o[2] = (__bf16)tile[tx * 4 + 2][c];
        o[3] = (__bf16)tile[tx * 4 + 3][c];
        *(bf16x4v*)(dst + (long long)(c0 + c) * lddst + r0 + tx * 4) = o;
    }
}

// ---------------------------------------------------------------------------
// bias rank-1 correction prep: w1_i = W_theta_i @ b_phi_i, w2_i = W_phi_i @ b_theta_i
// ---------------------------------------------------------------------------
__global__ __launch_bounds__(256) void uvc_w(
    const float* __restrict__ Wth, const float* __restrict__ Wph,
    const float* __restrict__ bth, const float* __restrict__ bph,
    float* __restrict__ w1w2) {
    const int i = blockIdx.y;
    const int w = threadIdx.x >> 6, l = threadIdx.x & 63;
    const int c = blockIdx.x * 4 + w;
    const float* Wt = Wth + (long long)i * 262144 + (long long)c * 512;
    const float* Wp = Wph + (long long)i * 262144 + (long long)c * 512;
    const float* bt = bth + i * 512;
    const float* bp = bph + i * 512;
    float s1 = 0.f, s2 = 0.f;
#pragma unroll
    for (int e = 0; e < 8; ++e) {
        int f = l + 64 * e;
        s1 = fmaf(Wt[f], bp[f], s1);
        s2 = fmaf(Wp[f], bt[f], s2);
    }
#pragma unroll
    for (int o = 32; o > 0; o >>= 1) { s1 += __shfl_down(s1, o); s2 += __shfl_down(s2, o); }
    if (l == 0) { w1w2[i * 1024 + c] = s1; w1w2[i * 1024 + 512 + c] = s2; }
}

__global__ void cvals_k(const float* __restrict__ bth, const float* __restrict__ bph,
                        float* __restrict__ cvals) {
    const int i = blockIdx.x;
    const int l = threadIdx.x;  // 64
    float s = 0.f;
#pragma unroll
    for (int e = 0; e < 8; ++e)
        s = fmaf(bth[i * 512 + l + 64 * e], bph[i * 512 + l + 64 * e], s);
#pragma unroll
    for (int o = 32; o > 0; o >>= 1) s += __shfl_down(s, o);
    if (l == 0) cvals[i] = s;
}

// u[i][n] = x_n . w1_i ; v[i][n] = x_n . w2_i  (all 24 dots per row in one pass)
__global__ __launch_bounds__(256) void uvc_x(
    const float* __restrict__ x, const float* __restrict__ w1w2,
    float* __restrict__ u, float* __restrict__ v) {
    __shared__ float wv[24][512];
    const int t = threadIdx.x;
    for (int idx = t; idx < 3072; idx += 256) {
        int j = idx >> 7, c4 = idx & 127;
        const float* src = (j < 12) ? (w1w2 + j * 1024 + c4 * 4)
                                    : (w1w2 + (j - 12) * 1024 + 512 + c4 * 4);
        *(float4*)&wv[j][c4 * 4] = *(const float4*)src;
    }
    __syncthreads();
    const int w = t >> 6, l = t & 63;
    const int row = blockIdx.x * 4 + w;
    float xv[8];
#pragma unroll
    for (int e = 0; e < 8; ++e) xv[e] = x[(long long)row * 512 + l + 64 * e];
#pragma unroll
    for (int j = 0; j < 24; ++j) {
        float p = 0.f;
#pragma unroll
        for (int e = 0; e < 8; ++e) p = fmaf(xv[e], wv[j][l + 64 * e], p);
#pragma unroll
        for (int o = 32; o > 0; o >>= 1) p += __shfl_down(p, o);
        if (l == 0) {
            if (j < 12) u[j * BS + row] = p;
            else        v[(j - 12) * BS + row] = p;
        }
    }
}

// ---------------------------------------------------------------------------
// bf16 MFMA GEMM, "nt" layout: C[M][N] = A[M][K] * Bt[N][K]^T  (f32 accum)
// 128x128 tile, BK=64, XOR-swizzled LDS (granule ^= row&7), source-swizzled
// global_load_lds (rule #21: linear dest + inv-swz source + swz read).
// MODE 1: sim: (acc+u+v+c)*scale, position mask -> -inf, f32 out
// MODE 2: bf16 out
// MODE 3: f32 out
// grid: (N/128, M/128, batch)
// ---------------------------------------------------------------------------
template <int MODE>
__global__ __launch_bounds__(256) void gemm_bf16(
    const __bf16* __restrict__ A, const __bf16* __restrict__ Bt, void* __restrict__ Cv,
    int lda, int ldb, int ldc, int K,
    long long sA, long long sB, long long sC,
    const float* __restrict__ uvec, const float* __restrict__ vvec,
    const float* __restrict__ cptr,
    const float4* __restrict__ posr, const int* __restrict__ OWp, float scale) {
    const int bz = blockIdx.z;
    A += sA * bz;
    Bt += sB * bz;
    const int m0 = blockIdx.y * 128, n0 = blockIdx.x * 128;

    __shared__ char lds[32768];  // A [128][128B] @0, B @16384

    const int t = threadIdx.x, l = t & 63, w = t >> 6;
    const int wm = w >> 1, wn = w & 1;

    f32x4 acc[4][4] = {};

    // staging: wave w stages rows [w*32, w*32+32); lane l -> row +(l>>3),
    // LDS granule (l&7) holds source granule (l&7)^(row&7) = (l&7)^(l>>3)
    const int g2 = (((l & 7) ^ (l >> 3)) << 4);
    const long long la2 = (long long)lda * 2, lb2 = (long long)ldb * 2;
    const char* Agp = (const char*)A + (long long)(m0 + w * 32 + (l >> 3)) * la2 + g2;
    const char* Bgp = (const char*)Bt + (long long)(n0 + w * 32 + (l >> 3)) * lb2 + g2;
    char* la = lds + w * 4096;
    char* lb = lds + 16384 + w * 4096;

    // fragment read offsets: row = ...+fr, source granule (ks*4+qh) at slot ^(row&7)
    const int fr = l & 15, qh = l >> 4, sx = l & 7;
    int offA[2][4], offB[2][4];
#pragma unroll
    for (int ks = 0; ks < 2; ++ks)
#pragma unroll
        for (int i = 0; i < 4; ++i) {
            int swz = (((ks << 2) | qh) ^ sx) << 4;
            offA[ks][i] = (wm * 64 + i * 16 + fr) * 128 + swz;
            offB[ks][i] = 16384 + (wn * 64 + i * 16 + fr) * 128 + swz;
        }

    for (int k0 = 0; k0 < K; k0 += 64) {
        const long long kb = (long long)k0 * 2;
        GLOAD16(Agp + kb, la);
        GLOAD16(Agp + kb + 8 * la2, la + 1024);
        GLOAD16(Agp + kb + 16 * la2, la + 2048);
        GLOAD16(Agp + kb + 24 * la2, la + 3072);
        GLOAD16(Bgp + kb, lb);
        GLOAD16(Bgp + kb + 8 * lb2, lb + 1024);
        GLOAD16(Bgp + kb + 16 * lb2, lb + 2048);
        GLOAD16(Bgp + kb + 24 * lb2, lb + 3072);
        __syncthreads();
#pragma unroll
        for (int ks = 0; ks < 2; ++ks) {
            bf16x8 af[4], bfr[4];
#pragma unroll
            for (int i = 0; i < 4; ++i) af[i] = *(const bf16x8*)(lds + offA[ks][i]);
#pragma unroll
            for (int j = 0; j < 4; ++j) bfr[j] = *(const bf16x8*)(lds + offB[ks][j]);
#pragma unroll
            for (int i = 0; i < 4; ++i)
#pragma unroll
                for (int j = 0; j < 4; ++j)
                    acc[i][j] = __builtin_amdgcn_mfma_f32_16x16x32_bf16(
                        af[i], bfr[j], acc[i][j], 0, 0, 0);
        }
        __syncthreads();
    }

    // C/D frag: col = n0+wn*64+j*16+(l&15), row = m0+wm*64+i*16+(l>>4)*4+r
    const int crow0 = m0 + wm * 64 + (l >> 4) * 4;
    const int ccol0 = n0 + wn * 64 + fr;

    if (MODE == 1) {
        float* C = (float*)Cv + sC * bz;
        const float4* pr = posr + bz * Ss;
        const float* uv = uvec + bz * Ss;
        const float* vv = vvec + bz * Ss;
        const float cadd = cptr[0];
        const float thr = 0.2f * (float)(*OWp);
        float4 pm[4];
        float vj[4];
#pragma unroll
        for (int j = 0; j < 4; ++j) {
            pm[j] = pr[ccol0 + j * 16];
            vj[j] = vv[ccol0 + j * 16];
        }
#pragma unroll
        for (int i = 0; i < 4; ++i)
#pragma unroll
            for (int r = 0; r < 4; ++r) {
                int row = crow0 + i * 16 + r;
                float4 pn = pr[row];
                float un = uv[row];
#pragma unroll
                for (int j = 0; j < 4; ++j) {
                    float e = fmaf(pn.y, pm[j].y, pn.x * pm[j].x);
                    float d2 = __fadd_rn(__fsub_rn(pn.z, __fmul_rn(2.0f, e)), pm[j].z);
                    float dist = sqrtf(fmaxf(d2, 0.0f));
                    float v = (acc[i][j][r] + un + vj[j] + cadd) * scale;
                    C[(long long)row * ldc + ccol0 + j * 16] =
                        (dist > thr) ? -INFINITY : v;
                }
            }
    } else if (MODE == 2) {
        __bf16* C = (__bf16*)Cv + sC * bz;
#pragma unroll
        for (int j = 0; j < 4; ++j)
#pragma unroll
            for (int i = 0; i < 4; ++i)
#pragma unroll
                for (int r = 0; r < 4; ++r) {
                    int row = crow0 + i * 16 + r;
                    C[(long long)row * ldc + ccol0 + j * 16] = (__bf16)acc[i][j][r];
                }
    } else {
        float* C = (float*)Cv + sC * bz;
#pragma unroll
        for (int j = 0; j < 4; ++j)
#pragma unroll
            for (int i = 0; i < 4; ++i)
#pragma unroll
                for (int r = 0; r < 4; ++r) {
                    int row = crow0 + i * 16 + r;
                    C[(long long)row * ldc + ccol0 + j * 16] = acc[i][j][r];
                }
    }
}

// ---------------------------------------------------------------------------
// Row softmax over rows of length 1280 (f32 in). bf16 out always; f32 back
// in place on last graph (relation output).
// ---------------------------------------------------------------------------
__global__ __launch_bounds__(256) void softmax_rows(
    float* __restrict__ sim, __bf16* __restrict__ relbf, int write_f32) {
    const int row = blockIdx.x;
    float* p = sim + (long long)row * Ss;
    __bf16* q = relbf + (long long)row * Ss;
    __shared__ float buf[Ss];
    __shared__ float wred[4];
    const int t = threadIdx.x;

    float m = -INFINITY;
    for (int j = t; j < Ss; j += 256) {
        float v = p[j];
        buf[j] = v;
        m = fmaxf(m, v);
    }
#pragma unroll
    for (int o = 32; o > 0; o >>= 1) m = fmaxf(m, __shfl_down(m, o));
    if ((t & 63) == 0) wred[t >> 6] = m;
    __syncthreads();
    const float m4 = fmaxf(fmaxf(wred[0], wred[1]), fmaxf(wred[2], wred[3]));
    __syncthreads();

    float s = 0.0f;
    for (int j = t; j < Ss; j += 256) {
        float e = expf(buf[j] - m4);
        buf[j] = e;
        s += e;
    }
#pragma unroll
    for (int o = 32; o > 0; o >>= 1) s += __shfl_down(s, o);
    if ((t & 63) == 0) wred[t >> 6] = s;
    __syncthreads();
    const float total = wred[0] + wred[1] + wred[2] + wred[3];
    const float inv = 1.0f / total;
    for (int j = t; j < Ss; j += 256) {
        float v = buf[j] * inv;
        q[j] = (__bf16)v;
        if (write_f32) p[j] = v;
    }
}

// ---------------------------------------------------------------------------
// LayerNorm reductions (two-stage, deterministic)
// ---------------------------------------------------------------------------
__global__ __launch_bounds__(256) void reduce1(const float* __restrict__ agg,
                                               float2* __restrict__ part) {
    const int b = blockIdx.y;
    const float4* p = (const float4*)(agg + (long long)b * SC);
    float s = 0.f, ss = 0.f;
    for (int j = blockIdx.x * 256 + threadIdx.x; j < SC / 4; j += 64 * 256) {
        float4 v = p[j];
        s += v.x + v.y + v.z + v.w;
        ss += v.x * v.x + v.y * v.y + v.z * v.z + v.w * v.w;
    }
#pragma unroll
    for (int o = 32; o > 0; o >>= 1) {
        s += __shfl_down(s, o);
        ss += __shfl_down(ss, o);
    }
    __shared__ float2 wred[4];
    if ((threadIdx.x & 63) == 0) wred[threadIdx.x >> 6] = make_float2(s, ss);
    __syncthreads();
    if (threadIdx.x == 0) {
        float S = wred[0].x + wred[1].x + wred[2].x + wred[3].x;
        float SS = wred[0].y + wred[1].y + wred[2].y + wred[3].y;
        part[b * 64 + blockIdx.x] = make_float2(S, SS);
    }
}

__global__ void reduce2(const float2* __restrict__ part, float2* __restrict__ stats) {
    const int b = blockIdx.x;
    float2 v = part[b * 64 + threadIdx.x];
    float s = v.x, ss = v.y;
#pragma unroll
    for (int o = 32; o > 0; o >>= 1) {
        s += __shfl_down(s, o);
        ss += __shfl_down(ss, o);
    }
    if (threadIdx.x == 0) {
        const float invn = 1.0f / (float)SC;
        float mu = s * invn;
        float var = ss * invn - mu * mu;
        stats[b] = make_float2(mu, 1.0f / sqrtf(var + 1e-5f));
    }
}

// ---------------------------------------------------------------------------
// out (+)= relu((agg - mu) * rstd * ln_scale + ln_bias)
// ---------------------------------------------------------------------------
__global__ __launch_bounds__(256) void ln_relu_acc(
    const float* __restrict__ agg, const float2* __restrict__ stats,
    const float* __restrict__ lnsc, const float* __restrict__ lnbi,
    float* __restrict__ out, int first) {
    for (int idx = blockIdx.x * 256 + threadIdx.x; idx < (Bb * SC) / 4;
         idx += gridDim.x * 256) {
        int b = idx / (SC / 4);
        int j = idx - b * (SC / 4);
        float2 st = stats[b];
        float4 a = ((const float4*)agg)[idx];
        float4 sc = ((const float4*)lnsc)[j];
        float4 bi = ((const float4*)lnbi)[j];
        float4 o;
        o.x = fmaxf((a.x - st.x) * st.y * sc.x + bi.x, 0.f);
        o.y = fmaxf((a.y - st.x) * st.y * sc.y + bi.y, 0.f);
        o.z = fmaxf((a.z - st.x) * st.y * sc.z + bi.z, 0.f);
        o.w = fmaxf((a.w - st.x) * st.y * sc.w + bi.w, 0.f);
        float4* op = (float4*)out + idx;
        if (!first) {
            float4 pv = *op;
            o.x += pv.x; o.y += pv.y; o.z += pv.z; o.w += pv.w;
        }
        *op = o;
    }
}

// ---------------------------------------------------------------------------
extern "C" void kernel_launch(void* const* d_in, const int* in_sizes, int n_in,
                              void* d_out, int out_size, void* d_ws, size_t ws_size,
                              hipStream_t stream) {
    const float* x        = (const float*)d_in[0];
    const float* box      = (const float*)d_in[1];
    const float* W_theta  = (const float*)d_in[2];
    const float* b_theta  = (const float*)d_in[3];
    const float* W_phi    = (const float*)d_in[4];
    const float* b_phi    = (const float*)d_in[5];
    const float* W_gcn    = (const float*)d_in[6];
    const float* ln_scale = (const float*)d_in[7];
    const float* ln_bias  = (const float*)d_in[8];
    const int*   OWp      = (const int*)d_in[10];

    float* out = (float*)d_out;            // [8,1280,512]
    float* rel_f32 = out + OUT0;           // [8,1280,1280] (output 1 region)

    char* ws = (char*)d_ws;
    float4* posr  = (float4*)(ws + 0);                  //   163840
    __bf16* x_bf  = (__bf16*)(ws + 163840);             // 10485760 [10240][512]
    __bf16* x_t   = (__bf16*)(ws + 10649600);           // 10485760 [8][512][1280]
    __bf16* Wgt   = (__bf16*)(ws + 21135360);           //  6291456 [12][512][512]
    __bf16* GiT   = (__bf16*)(ws + 27426816);           //  6291456 [12][512][512]
    float*  w1w2  = (float*)(ws + 33718272);            //    49152 [12][2][512]
    float*  cvals = (float*)(ws + 33767424);            //      256
    float*  u     = (float*)(ws + 33767680);            //   491520 [12][10240]
    float*  v     = (float*)(ws + 34259200);            //   491520
    __bf16* ybuf  = (__bf16*)(ws + 34750720);           // 10485760 [10240][512]
    __bf16* relbf = (__bf16*)(ws + 45236480);           // 26214400 [8][1280][1280]
    __bf16* agg1  = (__bf16*)(ws + 71450880);           // 10485760 [10240][512]
    float*  aggF  = (float*)(ws + 81936640);            // 20971520 [10240][512] f32
    float2* part  = (float2*)(ws + 102908160);
    float2* stats = part + Bb * 64;
    // prep-only aliases (dead once the loop starts; stream-ordered)
    __bf16* Wth_bf = (__bf16*)(ws + 81936640);          // 6291456 (aliases aggF)
    __bf16* Wph_bf = (__bf16*)(ws + 88228096);          // 6291456

    // ---- one-time prep ----
    compute_pos<<<dim3(40), dim3(256), 0, stream>>>(box, posr);
    cvt_bf16<<<dim3(2048), dim3(256), 0, stream>>>(x, x_bf, OUT0 / 4);
    transpose_cvt<<<dim3(20, 8, 8), dim3(256), 0, stream>>>(
        x, x_t, Cc, Ss, (long long)SC, (long long)SC);
    cvt_bf16<<<dim3(2048), dim3(256), 0, stream>>>(W_theta, Wth_bf, 786432);
    cvt_bf16<<<dim3(2048), dim3(256), 0, stream>>>(W_phi, Wph_bf, 786432);
    transpose_cvt<<<dim3(8, 8, 12), dim3(256), 0, stream>>>(
        W_gcn, Wgt, Cc, Cc, (long long)Cc * Cc, (long long)Cc * Cc);
    // GiT[i][d][c] = sum_f Wphi[d][f] * Wtheta[c][f]  (Bt-operand for y = x@G)
    gemm_bf16<2><<<dim3(4, 4, 12), dim3(256), 0, stream>>>(
        Wph_bf, Wth_bf, GiT, Cc, Cc, Cc, Cc, 262144, 262144, 262144,
        nullptr, nullptr, nullptr, nullptr, nullptr, 0.f);
    // bias rank-1 terms (exact; zeros for this input)
    uvc_w<<<dim3(128, 12), dim3(256), 0, stream>>>(W_theta, W_phi, b_theta, b_phi, w1w2);
    cvals_k<<<dim3(12), dim3(64), 0, stream>>>(b_theta, b_phi, cvals);
    uvc_x<<<dim3(2560), dim3(256), 0, stream>>>(x, w1w2, u, v);

    const float inv_sqrt = 0.044194173824159216f;  // 1/sqrt(512)

    for (int i = 0; i < NG; ++i) {
        const __bf16* Gi  = GiT + (long long)i * Cc * Cc;
        const __bf16* Wg_i = Wgt + (long long)i * Cc * Cc;
        // y = x @ G_i -> bf16 [10240][512]
        gemm_bf16<2><<<dim3(4, 80, 1), dim3(256), 0, stream>>>(
            x_bf, Gi, ybuf, Cc, Cc, Cc, Cc, 0, 0, 0,
            nullptr, nullptr, nullptr, nullptr, nullptr, 0.f);
        // sim = (y @ x^T + u + v + c) * scale, masked -> rel_f32
        gemm_bf16<1><<<dim3(10, 10, 8), dim3(256), 0, stream>>>(
            ybuf, x_bf, rel_f32, Cc, Cc, Ss, Cc,
            (long long)Ss * Cc, (long long)Ss * Cc, (long long)Ss * Ss,
            u + (long long)i * BS, v + (long long)i * BS, cvals + i,
            posr, OWp, inv_sqrt);
        // softmax rows
        softmax_rows<<<dim3(BS), dim3(256), 0, stream>>>(rel_f32, relbf,
                                                         i == NG - 1 ? 1 : 0);
        // agg1 = relation @ x -> bf16
        gemm_bf16<2><<<dim3(4, 10, 8), dim3(256), 0, stream>>>(
            relbf, x_t, agg1, Ss, Ss, Cc, Ss,
            (long long)Ss * Ss, (long long)Cc * Ss, (long long)Ss * Cc,
            nullptr, nullptr, nullptr, nullptr, nullptr, 0.f);
        // agg = agg1 @ W_gcn -> f32
        gemm_bf16<3><<<dim3(4, 80, 1), dim3(256), 0, stream>>>(
            agg1, Wg_i, aggF, Cc, Cc, Cc, Cc, 0, 0, 0,
            nullptr, nullptr, nullptr, nullptr, nullptr, 0.f);
        // LayerNorm + relu + accumulate
        reduce1<<<dim3(64, 8), dim3(256), 0, stream>>>(aggF, part);
        reduce2<<<dim3(8), dim3(64), 0, stream>>>(part, stats);
        ln_relu_acc<<<dim3(2048), dim3(256), 0, stream>>>(
            aggF, stats, ln_scale + (long long)i * SC, ln_bias + (long long)i * SC,
            out, i == 0 ? 1 : 0);
    }
}

// Round 6
// 1690.917 us; speedup vs baseline: 5.3806x; 1.1525x over previous
//
#include <hip/hip_runtime.h>
#include <math.h>

// Problem constants
#define NG   12
#define Bb   8
#define Ss   1280
#define Cc   512
#define BS   10240            // B*S
#define SC   655360           // S*C per batch
#define OUT0 5242880          // B*S*C floats (output 0)

typedef __bf16 bf16x8 __attribute__((ext_vector_type(8)));
typedef __bf16 bf16x4v __attribute__((ext_vector_type(4)));
typedef float  f32x4  __attribute__((ext_vector_type(4)));

#define GLOAD16(gp, lp)                                                        \
    __builtin_amdgcn_global_load_lds(                                          \
        (const __attribute__((address_space(1))) void*)(gp),                   \
        (__attribute__((address_space(3))) void*)(lp), 16, 0, 0)

// ---------------------------------------------------------------------------
// pos precompute: cx, cy, r = cx*cx + cy*cy
// ---------------------------------------------------------------------------
__global__ __launch_bounds__(256) void compute_pos(const float* __restrict__ box,
                                                   float4* __restrict__ posr) {
    int i = blockIdx.x * 256 + threadIdx.x;
    if (i < BS) {
        float x0 = box[i * 4 + 0], y0 = box[i * 4 + 1];
        float x1 = box[i * 4 + 2], y1 = box[i * 4 + 3];
        float cx = (x0 + x1) * 0.5f;
        float cy = (y0 + y1) * 0.5f;
        float px = __fmul_rn(cx, cx);
        float py = __fmul_rn(cy, cy);
        posr[i] = make_float4(cx, cy, __fadd_rn(px, py), 0.0f);
    }
}

// ---------------------------------------------------------------------------
// f32 -> bf16 elementwise convert (vectorized)
// ---------------------------------------------------------------------------
__global__ __launch_bounds__(256) void cvt_bf16(const float* __restrict__ src,
                                                __bf16* __restrict__ dst, int n4) {
    for (int i = blockIdx.x * 256 + threadIdx.x; i < n4; i += gridDim.x * 256) {
        float4 v = ((const float4*)src)[i];
        bf16x4v o;
        o[0] = (__bf16)v.x; o[1] = (__bf16)v.y; o[2] = (__bf16)v.z; o[3] = (__bf16)v.w;
        *(bf16x4v*)(dst + i * 4) = o;
    }
}

// ---------------------------------------------------------------------------
// Tiled transpose + convert: dst[c][r] (bf16) = src[r][c] (f32). 64x64 tiles.
// ---------------------------------------------------------------------------
__global__ __launch_bounds__(256) void transpose_cvt(
    const float* __restrict__ src, __bf16* __restrict__ dst,
    int ldsrc, int lddst, long long sSrc, long long sDst) {
    src += sSrc * blockIdx.z;
    dst += sDst * blockIdx.z;
    __shared__ float tile[64][65];
    const int t = threadIdx.x, tx = t & 15, ty = t >> 4;
    const int r0 = blockIdx.x * 64, c0 = blockIdx.y * 64;
#pragma unroll
    for (int rr = 0; rr < 4; ++rr) {
        int r = ty + rr * 16;
        float4 v = *(const float4*)(src + (long long)(r0 + r) * ldsrc + c0 + tx * 4);
        tile[r][tx * 4 + 0] = v.x;
        tile[r][tx * 4 + 1] = v.y;
        tile[r][tx * 4 + 2] = v.z;
        tile[r][tx * 4 + 3] = v.w;
    }
    __syncthreads();
#pragma unroll
    for (int rr = 0; rr < 4; ++rr) {
        int c = ty + rr * 16;
        bf16x4v o;
        o[0] = (__bf16)tile[tx * 4 + 0][c];
        o[1] = (__bf16)tile[tx * 4 + 1][c];
        o[2] = (__bf16)tile[tx * 4 + 2][c];
        o[3] = (__bf16)tile[tx * 4 + 3][c];
        *(bf16x4v*)(dst + (long long)(c0 + c) * lddst + r0 + tx * 4) = o;
    }
}

// ---------------------------------------------------------------------------
// bias rank-1 correction prep: w1_i = W_theta_i @ b_phi_i, w2_i = W_phi_i @ b_theta_i
// ---------------------------------------------------------------------------
__global__ __launch_bounds__(256) void uvc_w(
    const float* __restrict__ Wth, const float* __restrict__ Wph,
    const float* __restrict__ bth, const float* __restrict__ bph,
    float* __restrict__ w1w2) {
    const int i = blockIdx.y;
    const int w = threadIdx.x >> 6, l = threadIdx.x & 63;
    const int c = blockIdx.x * 4 + w;
    const float* Wt = Wth + (long long)i * 262144 + (long long)c * 512;
    const float* Wp = Wph + (long long)i * 262144 + (long long)c * 512;
    const float* bt = bth + i * 512;
    const float* bp = bph + i * 512;
    float s1 = 0.f, s2 = 0.f;
#pragma unroll
    for (int e = 0; e < 8; ++e) {
        int f = l + 64 * e;
        s1 = fmaf(Wt[f], bp[f], s1);
        s2 = fmaf(Wp[f], bt[f], s2);
    }
#pragma unroll
    for (int o = 32; o > 0; o >>= 1) { s1 += __shfl_down(s1, o); s2 += __shfl_down(s2, o); }
    if (l == 0) { w1w2[i * 1024 + c] = s1; w1w2[i * 1024 + 512 + c] = s2; }
}

__global__ void cvals_k(const float* __restrict__ bth, const float* __restrict__ bph,
                        float* __restrict__ cvals) {
    const int i = blockIdx.x;
    const int l = threadIdx.x;  // 64
    float s = 0.f;
#pragma unroll
    for (int e = 0; e < 8; ++e)
        s = fmaf(bth[i * 512 + l + 64 * e], bph[i * 512 + l + 64 * e], s);
#pragma unroll
    for (int o = 32; o > 0; o >>= 1) s += __shfl_down(s, o);
    if (l == 0) cvals[i] = s;
}

// u[i][n] = x_n . w1_i ; v[i][n] = x_n . w2_i
__global__ __launch_bounds__(256) void uvc_x(
    const float* __restrict__ x, const float* __restrict__ w1w2,
    float* __restrict__ u, float* __restrict__ v) {
    __shared__ float wv[24][512];
    const int t = threadIdx.x;
    for (int idx = t; idx < 3072; idx += 256) {
        int j = idx >> 7, c4 = idx & 127;
        const float* src = (j < 12) ? (w1w2 + j * 1024 + c4 * 4)
                                    : (w1w2 + (j - 12) * 1024 + 512 + c4 * 4);
        *(float4*)&wv[j][c4 * 4] = *(const float4*)src;
    }
    __syncthreads();
    const int w = t >> 6, l = t & 63;
    const int row = blockIdx.x * 4 + w;
    float xv[8];
#pragma unroll
    for (int e = 0; e < 8; ++e) xv[e] = x[(long long)row * 512 + l + 64 * e];
#pragma unroll
    for (int j = 0; j < 24; ++j) {
        float p = 0.f;
#pragma unroll
        for (int e = 0; e < 8; ++e) p = fmaf(xv[e], wv[j][l + 64 * e], p);
#pragma unroll
        for (int o = 32; o > 0; o >>= 1) p += __shfl_down(p, o);
        if (l == 0) {
            if (j < 12) u[j * BS + row] = p;
            else        v[(j - 12) * BS + row] = p;
        }
    }
}

// ---------------------------------------------------------------------------
// bf16 MFMA GEMM, "nt": C[M][N] = A[M][K] * Bt[N][K]^T (f32 accum)
// 128x128 tile, BK=64, XOR-swizzled LDS, DOUBLE-BUFFERED 2-phase K-loop
// (STAGE next-tile issued before compute, one barrier per K-step at end),
// XCD-contiguous block swizzle (requires total blocks % 8 == 0).
// MODE 1: sim epilogue: (acc+u+v+c)*scale, mask -> -inf; f32 or bf16 out (obf)
// MODE 2: bf16 out
// MODE 3: f32 out + fused LN partial stats (atomicAdd per block)
// ---------------------------------------------------------------------------
template <int MODE>
__global__ __launch_bounds__(256) void gemm_bf16(
    const __bf16* __restrict__ A, const __bf16* __restrict__ Bt, void* __restrict__ Cv,
    int lda, int ldb, int ldc, int K,
    long long sA, long long sB, long long sC,
    const float* __restrict__ uvec, const float* __restrict__ vvec,
    const float* __restrict__ cptr,
    const float4* __restrict__ posr, const int* __restrict__ OWp, float scale,
    __bf16* __restrict__ obf_out, int obf, float* __restrict__ statsraw) {

    // XCD-contiguous swizzle: each XCD gets a contiguous 1/8 chunk of the grid
    const int gx = gridDim.x, gy = gridDim.y;
    int id = blockIdx.x + gx * (blockIdx.y + gy * blockIdx.z);
    const int q = (gx * gy * gridDim.z) >> 3;
    id = (id & 7) * q + (id >> 3);
    const int bx = id % gx;
    const int rem = id / gx;
    const int by = rem % gy;
    const int bz = rem / gy;

    A += sA * bz;
    Bt += sB * bz;
    const int m0 = by * 128, n0 = bx * 128;

    __shared__ char lds[65536];  // 2 buffers x (A 16K @0 | B 16K @16384)

    const int t = threadIdx.x, l = t & 63, w = t >> 6;
    const int wm = w >> 1, wn = w & 1;

    f32x4 acc[4][4] = {};

    // staging: wave w rows [w*32, w*32+32); lane l -> row +(l>>3),
    // LDS granule (l&7) gets source granule (l&7)^(row&7)
    const int g2 = (((l & 7) ^ (l >> 3)) << 4);
    const long long la2 = (long long)lda * 2, lb2 = (long long)ldb * 2;
    const char* Agp = (const char*)A + (long long)(m0 + w * 32 + (l >> 3)) * la2 + g2;
    const char* Bgp = (const char*)Bt + (long long)(n0 + w * 32 + (l >> 3)) * lb2 + g2;

    // fragment reads: row ...+fr, granule g=ks*4+qh at slot g^(row&7)
    const int fr = l & 15, qh = l >> 4, sx = l & 7;
    int offA[2][4], offB[2][4];
#pragma unroll
    for (int ks = 0; ks < 2; ++ks)
#pragma unroll
        for (int i = 0; i < 4; ++i) {
            int swz = (((ks << 2) | qh) ^ sx) << 4;
            offA[ks][i] = (wm * 64 + i * 16 + fr) * 128 + swz;
            offB[ks][i] = 16384 + (wn * 64 + i * 16 + fr) * 128 + swz;
        }

#define STAGE(kt, bufo)                                                        \
    {                                                                          \
        const long long kb = (long long)(kt) * 128;                            \
        char* lA = lds + (bufo) + w * 4096;                                    \
        char* lB = lds + (bufo) + 16384 + w * 4096;                            \
        GLOAD16(Agp + kb, lA);                                                 \
        GLOAD16(Agp + kb + 8 * la2, lA + 1024);                                \
        GLOAD16(Agp + kb + 16 * la2, lA + 2048);                               \
        GLOAD16(Agp + kb + 24 * la2, lA + 3072);                               \
        GLOAD16(Bgp + kb, lB);                                                 \
        GLOAD16(Bgp + kb + 8 * lb2, lB + 1024);                                \
        GLOAD16(Bgp + kb + 16 * lb2, lB + 2048);                               \
        GLOAD16(Bgp + kb + 24 * lb2, lB + 3072);                               \
    }

    const int KT = K >> 6;
    STAGE(0, 0);
    __syncthreads();
    for (int kt = 0; kt < KT; ++kt) {
        const int cur = (kt & 1) << 15;
        if (kt + 1 < KT) STAGE(kt + 1, cur ^ 32768);
#pragma unroll
        for (int ks = 0; ks < 2; ++ks) {
            bf16x8 af[4], bfr[4];
#pragma unroll
            for (int i = 0; i < 4; ++i) af[i] = *(const bf16x8*)(lds + cur + offA[ks][i]);
#pragma unroll
            for (int j = 0; j < 4; ++j) bfr[j] = *(const bf16x8*)(lds + cur + offB[ks][j]);
#pragma unroll
            for (int i = 0; i < 4; ++i)
#pragma unroll
                for (int j = 0; j < 4; ++j)
                    acc[i][j] = __builtin_amdgcn_mfma_f32_16x16x32_bf16(
                        af[i], bfr[j], acc[i][j], 0, 0, 0);
        }
        __syncthreads();
    }
#undef STAGE

    // C/D frag: col = n0+wn*64+j*16+(l&15), row = m0+wm*64+i*16+(l>>4)*4+r
    const int crow0 = m0 + wm * 64 + (l >> 4) * 4;
    const int ccol0 = n0 + wn * 64 + fr;

    if (MODE == 1) {
        const float4* pr = posr + bz * Ss;
        const float* uv = uvec + bz * Ss;
        const float* vv = vvec + bz * Ss;
        const float cadd = cptr[0];
        const float thr = 0.2f * (float)(*OWp);
        float4 pm[4];
        float vj[4];
#pragma unroll
        for (int j = 0; j < 4; ++j) {
            pm[j] = pr[ccol0 + j * 16];
            vj[j] = vv[ccol0 + j * 16];
        }
        float* Cf = (float*)Cv + sC * bz;
        __bf16* Cb = obf_out + sC * bz;
#pragma unroll
        for (int i = 0; i < 4; ++i)
#pragma unroll
            for (int r = 0; r < 4; ++r) {
                int row = crow0 + i * 16 + r;
                float4 pn = pr[row];
                float un = uv[row];
#pragma unroll
                for (int j = 0; j < 4; ++j) {
                    float e = fmaf(pn.y, pm[j].y, pn.x * pm[j].x);
                    float d2 = __fadd_rn(__fsub_rn(pn.z, __fmul_rn(2.0f, e)), pm[j].z);
                    float dist = sqrtf(fmaxf(d2, 0.0f));
                    float v = (acc[i][j][r] + un + vj[j] + cadd) * scale;
                    float ov = (dist > thr) ? -INFINITY : v;
                    if (obf) Cb[(long long)row * ldc + ccol0 + j * 16] = (__bf16)ov;
                    else     Cf[(long long)row * ldc + ccol0 + j * 16] = ov;
                }
            }
    } else if (MODE == 2) {
        __bf16* C = (__bf16*)Cv + sC * bz;
#pragma unroll
        for (int j = 0; j < 4; ++j)
#pragma unroll
            for (int i = 0; i < 4; ++i)
#pragma unroll
                for (int r = 0; r < 4; ++r) {
                    int row = crow0 + i * 16 + r;
                    C[(long long)row * ldc + ccol0 + j * 16] = (__bf16)acc[i][j][r];
                }
    } else {
        float* C = (float*)Cv + sC * bz;
        float s = 0.f, ss = 0.f;
#pragma unroll
        for (int j = 0; j < 4; ++j)
#pragma unroll
            for (int i = 0; i < 4; ++i)
#pragma unroll
                for (int r = 0; r < 4; ++r) {
                    int row = crow0 + i * 16 + r;
                    float ov = acc[i][j][r];
                    C[(long long)row * ldc + ccol0 + j * 16] = ov;
                    s += ov;
                    ss = fmaf(ov, ov, ss);
                }
        // fused LN partial stats
#pragma unroll
        for (int o = 32; o > 0; o >>= 1) {
            s += __shfl_down(s, o);
            ss += __shfl_down(ss, o);
        }
        float* redf = (float*)lds;
        if (l == 0) { redf[w * 2] = s; redf[w * 2 + 1] = ss; }
        __syncthreads();
        if (t == 0) {
            float S = redf[0] + redf[2] + redf[4] + redf[6];
            float SS = redf[1] + redf[3] + redf[5] + redf[7];
            atomicAdd(&statsraw[bz * 2], S);
            atomicAdd(&statsraw[bz * 2 + 1], SS);
        }
    }
}

// ---------------------------------------------------------------------------
// Row softmax, rows of 1280. INBF=1: bf16 in, bf16 out. INBF=0: f32 in,
// bf16 out + f32 in-place (final relation output).
// ---------------------------------------------------------------------------
template <int INBF>
__global__ __launch_bounds__(256) void softmax_rows(
    const __bf16* __restrict__ inbf, float* __restrict__ f32io,
    __bf16* __restrict__ relbf) {
    const int row = blockIdx.x;
    __shared__ float buf[Ss];
    __shared__ float wred[4];
    const int t = threadIdx.x;

    float m = -INFINITY;
    if (INBF) {
        const __bf16* p = inbf + (long long)row * Ss;
        for (int j = t; j < Ss; j += 256) {
            float v = (float)p[j];
            buf[j] = v;
            m = fmaxf(m, v);
        }
    } else {
        const float* p = f32io + (long long)row * Ss;
        for (int j = t; j < Ss; j += 256) {
            float v = p[j];
            buf[j] = v;
            m = fmaxf(m, v);
        }
    }
#pragma unroll
    for (int o = 32; o > 0; o >>= 1) m = fmaxf(m, __shfl_down(m, o));
    if ((t & 63) == 0) wred[t >> 6] = m;
    __syncthreads();
    const float m4 = fmaxf(fmaxf(wred[0], wred[1]), fmaxf(wred[2], wred[3]));
    __syncthreads();

    float s = 0.0f;
    for (int j = t; j < Ss; j += 256) {
        float e = expf(buf[j] - m4);
        buf[j] = e;
        s += e;
    }
#pragma unroll
    for (int o = 32; o > 0; o >>= 1) s += __shfl_down(s, o);
    if ((t & 63) == 0) wred[t >> 6] = s;
    __syncthreads();
    const float total = wred[0] + wred[1] + wred[2] + wred[3];
    const float inv = 1.0f / total;
    __bf16* qo = relbf + (long long)row * Ss;
    float* po = f32io + (long long)row * Ss;
    for (int j = t; j < Ss; j += 256) {
        float v = buf[j] * inv;
        qo[j] = (__bf16)v;
        if (!INBF) po[j] = v;
    }
}

// ---------------------------------------------------------------------------
// finalize LN stats from atomically-accumulated raw sums; reset raw for next iter
// ---------------------------------------------------------------------------
__global__ void stats_final(float* __restrict__ raw, float2* __restrict__ stats) {
    const int b = threadIdx.x;
    if (b < Bb) {
        float S = raw[b * 2], SS = raw[b * 2 + 1];
        const float invn = 1.0f / (float)SC;
        float mu = S * invn;
        float var = SS * invn - mu * mu;
        stats[b] = make_float2(mu, 1.0f / sqrtf(var + 1e-5f));
        raw[b * 2] = 0.f;
        raw[b * 2 + 1] = 0.f;
    }
}

// ---------------------------------------------------------------------------
// out (+)= relu((agg - mu) * rstd * ln_scale + ln_bias)
// ---------------------------------------------------------------------------
__global__ __launch_bounds__(256) void ln_relu_acc(
    const float* __restrict__ agg, const float2* __restrict__ stats,
    const float* __restrict__ lnsc, const float* __restrict__ lnbi,
    float* __restrict__ out, int first) {
    for (int idx = blockIdx.x * 256 + threadIdx.x; idx < (Bb * SC) / 4;
         idx += gridDim.x * 256) {
        int b = idx / (SC / 4);
        int j = idx - b * (SC / 4);
        float2 st = stats[b];
        float4 a = ((const float4*)agg)[idx];
        float4 sc = ((const float4*)lnsc)[j];
        float4 bi = ((const float4*)lnbi)[j];
        float4 o;
        o.x = fmaxf((a.x - st.x) * st.y * sc.x + bi.x, 0.f);
        o.y = fmaxf((a.y - st.x) * st.y * sc.y + bi.y, 0.f);
        o.z = fmaxf((a.z - st.x) * st.y * sc.z + bi.z, 0.f);
        o.w = fmaxf((a.w - st.x) * st.y * sc.w + bi.w, 0.f);
        float4* op = (float4*)out + idx;
        if (!first) {
            float4 pv = *op;
            o.x += pv.x; o.y += pv.y; o.z += pv.z; o.w += pv.w;
        }
        *op = o;
    }
}

// ---------------------------------------------------------------------------
extern "C" void kernel_launch(void* const* d_in, const int* in_sizes, int n_in,
                              void* d_out, int out_size, void* d_ws, size_t ws_size,
                              hipStream_t stream) {
    const float* x        = (const float*)d_in[0];
    const float* box      = (const float*)d_in[1];
    const float* W_theta  = (const float*)d_in[2];
    const float* b_theta  = (const float*)d_in[3];
    const float* W_phi    = (const float*)d_in[4];
    const float* b_phi    = (const float*)d_in[5];
    const float* W_gcn    = (const float*)d_in[6];
    const float* ln_scale = (const float*)d_in[7];
    const float* ln_bias  = (const float*)d_in[8];
    const int*   OWp      = (const int*)d_in[10];

    float* out = (float*)d_out;            // [8,1280,512]
    float* rel_f32 = out + OUT0;           // [8,1280,1280] (output 1 region)
    __bf16* simbf = (__bf16*)rel_f32;      // bf16 sim scratch inside out region (iters 0..10)

    char* ws = (char*)d_ws;
    float4* posr   = (float4*)(ws + 0);                 //   163840
    __bf16* x_bf   = (__bf16*)(ws + 163840);            // 10485760 [10240][512]
    __bf16* Wgt    = (__bf16*)(ws + 10649600);          //  6291456 [12][512][512] (W_gcn^T)
    __bf16* GiT    = (__bf16*)(ws + 16941056);          //  6291456 [12][512][512]
    float*  w1w2   = (float*)(ws + 23232512);           //    49152
    float*  cvals  = (float*)(ws + 23281664);           //      256
    float*  u      = (float*)(ws + 23281920);           //   491520 [12][10240]
    float*  v      = (float*)(ws + 23773440);           //   491520
    float*  sraw   = (float*)(ws + 24264960);           //       64 (atomic stats)
    float2* stats  = (float2*)(ws + 24265216);          //       64
    __bf16* ybuf   = (__bf16*)(ws + 24265728);          // 10485760 [10240][512]
    __bf16* z_t    = (__bf16*)(ws + 34751488);          // 10485760 [8][512][1280]
    __bf16* relbf  = (__bf16*)(ws + 45237248);          // 26214400 [8][1280][1280]
    float*  aggF   = (float*)(ws + 71451648);           // 20971520 [10240][512] f32
    // prep-only aliases (inside aggF region; dead once loop starts)
    __bf16* Wth_bf = (__bf16*)(ws + 71451648);          //  6291456
    __bf16* Wph_bf = (__bf16*)(ws + 77743104);          //  6291456

    hipMemsetAsync(sraw, 0, 64, stream);

    // ---- one-time prep ----
    compute_pos<<<dim3(40), dim3(256), 0, stream>>>(box, posr);
    cvt_bf16<<<dim3(2048), dim3(256), 0, stream>>>(x, x_bf, OUT0 / 4);
    cvt_bf16<<<dim3(2048), dim3(256), 0, stream>>>(W_theta, Wth_bf, 786432);
    cvt_bf16<<<dim3(2048), dim3(256), 0, stream>>>(W_phi, Wph_bf, 786432);
    transpose_cvt<<<dim3(8, 8, 12), dim3(256), 0, stream>>>(
        W_gcn, Wgt, Cc, Cc, (long long)Cc * Cc, (long long)Cc * Cc);
    // GiT[i][d][c] = sum_f Wphi[d][f] * Wtheta[c][f]
    gemm_bf16<2><<<dim3(4, 4, 12), dim3(256), 0, stream>>>(
        Wph_bf, Wth_bf, GiT, Cc, Cc, Cc, Cc, 262144, 262144, 262144,
        nullptr, nullptr, nullptr, nullptr, nullptr, 0.f, nullptr, 0, nullptr);
    // bias rank-1 terms (exact; zeros for this input)
    uvc_w<<<dim3(128, 12), dim3(256), 0, stream>>>(W_theta, W_phi, b_theta, b_phi, w1w2);
    cvals_k<<<dim3(12), dim3(64), 0, stream>>>(b_theta, b_phi, cvals);
    uvc_x<<<dim3(2560), dim3(256), 0, stream>>>(x, w1w2, u, v);

    const float inv_sqrt = 0.044194173824159216f;  // 1/sqrt(512)

    for (int i = 0; i < NG; ++i) {
        const __bf16* Gi   = GiT + (long long)i * Cc * Cc;
        const __bf16* Wg_i = Wgt + (long long)i * Cc * Cc;
        const int last = (i == NG - 1);
        // y = x @ G_i -> bf16 [10240][512]
        gemm_bf16<2><<<dim3(4, 80, 1), dim3(256), 0, stream>>>(
            x_bf, Gi, ybuf, Cc, Cc, Cc, Cc, 0, 0, 0,
            nullptr, nullptr, nullptr, nullptr, nullptr, 0.f, nullptr, 0, nullptr);
        // sim = (y @ x^T + u + v + c)*scale, masked; bf16 (iters 0..10) or f32 (last)
        gemm_bf16<1><<<dim3(10, 10, 8), dim3(256), 0, stream>>>(
            ybuf, x_bf, rel_f32, Cc, Cc, Ss, Cc,
            (long long)Ss * Cc, (long long)Ss * Cc, (long long)Ss * Ss,
            u + (long long)i * BS, v + (long long)i * BS, cvals + i,
            posr, OWp, inv_sqrt, simbf, last ? 0 : 1, nullptr);
        // softmax rows -> relbf (+ f32 in place on last)
        if (last)
            softmax_rows<0><<<dim3(BS), dim3(256), 0, stream>>>(nullptr, rel_f32, relbf);
        else
            softmax_rows<1><<<dim3(BS), dim3(256), 0, stream>>>(simbf, nullptr, relbf);
        // z_t[b][c][s] = (x @ W_gcn_i)^T -> bf16
        gemm_bf16<2><<<dim3(10, 4, 8), dim3(256), 0, stream>>>(
            Wg_i, x_bf, z_t, Cc, Cc, Ss, Cc,
            0, (long long)SC, (long long)Cc * Ss,
            nullptr, nullptr, nullptr, nullptr, nullptr, 0.f, nullptr, 0, nullptr);
        // agg = P @ z_i -> f32 (+ fused LN partial stats)
        gemm_bf16<3><<<dim3(4, 10, 8), dim3(256), 0, stream>>>(
            relbf, z_t, aggF, Ss, Ss, Cc, Ss,
            (long long)Ss * Ss, (long long)Cc * Ss, (long long)SC,
            nullptr, nullptr, nullptr, nullptr, nullptr, 0.f, nullptr, 0, sraw);
        // finalize stats (and reset raw accumulators)
        stats_final<<<dim3(1), dim3(64), 0, stream>>>(sraw, stats);
        // out (+)= relu(LN(agg))
        ln_relu_acc<<<dim3(2048), dim3(256), 0, stream>>>(
            aggF, stats, ln_scale + (long long)i * SC, ln_bias + (long long)i * SC,
            out, i == 0 ? 1 : 0);
    }
}

// Round 7
// 1643.171 us; speedup vs baseline: 5.5370x; 1.0291x over previous
//
#include <hip/hip_runtime.h>
#include <math.h>

// Problem constants
#define NG   12
#define Bb   8
#define Ss   1280
#define Cc   512
#define BS   10240            // B*S
#define SC   655360           // S*C per batch
#define OUT0 5242880          // B*S*C floats (output 0)

typedef __bf16 bf16x8 __attribute__((ext_vector_type(8)));
typedef __bf16 bf16x4v __attribute__((ext_vector_type(4)));
typedef float  f32x4  __attribute__((ext_vector_type(4)));

#define GLOAD16(gp, lp)                                                        \
    __builtin_amdgcn_global_load_lds(                                          \
        (const __attribute__((address_space(1))) void*)(gp),                   \
        (__attribute__((address_space(3))) void*)(lp), 16, 0, 0)

// ---------------------------------------------------------------------------
__global__ __launch_bounds__(256) void compute_pos(const float* __restrict__ box,
                                                   float4* __restrict__ posr) {
    int i = blockIdx.x * 256 + threadIdx.x;
    if (i < BS) {
        float x0 = box[i * 4 + 0], y0 = box[i * 4 + 1];
        float x1 = box[i * 4 + 2], y1 = box[i * 4 + 3];
        float cx = (x0 + x1) * 0.5f;
        float cy = (y0 + y1) * 0.5f;
        float px = __fmul_rn(cx, cx);
        float py = __fmul_rn(cy, cy);
        posr[i] = make_float4(cx, cy, __fadd_rn(px, py), 0.0f);
    }
}

// ---------------------------------------------------------------------------
__global__ __launch_bounds__(256) void cvt_bf16(const float* __restrict__ src,
                                                __bf16* __restrict__ dst, int n4) {
    for (int i = blockIdx.x * 256 + threadIdx.x; i < n4; i += gridDim.x * 256) {
        float4 v = ((const float4*)src)[i];
        bf16x4v o;
        o[0] = (__bf16)v.x; o[1] = (__bf16)v.y; o[2] = (__bf16)v.z; o[3] = (__bf16)v.w;
        *(bf16x4v*)(dst + i * 4) = o;
    }
}

// ---------------------------------------------------------------------------
// Tiled transpose + convert: dst[c][r] (bf16) = src[r][c] (f32). 64x64 tiles.
// ---------------------------------------------------------------------------
__global__ __launch_bounds__(256) void transpose_cvt(
    const float* __restrict__ src, __bf16* __restrict__ dst,
    int ldsrc, int lddst, long long sSrc, long long sDst) {
    src += sSrc * blockIdx.z;
    dst += sDst * blockIdx.z;
    __shared__ float tile[64][65];
    const int t = threadIdx.x, tx = t & 15, ty = t >> 4;
    const int r0 = blockIdx.x * 64, c0 = blockIdx.y * 64;
#pragma unroll
    for (int rr = 0; rr < 4; ++rr) {
        int r = ty + rr * 16;
        float4 v = *(const float4*)(src + (long long)(r0 + r) * ldsrc + c0 + tx * 4);
        tile[r][tx * 4 + 0] = v.x;
        tile[r][tx * 4 + 1] = v.y;
        tile[r][tx * 4 + 2] = v.z;
        tile[r][tx * 4 + 3] = v.w;
    }
    __syncthreads();
#pragma unroll
    for (int rr = 0; rr < 4; ++rr) {
        int c = ty + rr * 16;
        bf16x4v o;
        o[0] = (__bf16)tile[tx * 4 + 0][c];
        o[1] = (__bf16)tile[tx * 4 + 1][c];
        o[2] = (__bf16)tile[tx * 4 + 2][c];
        o[3] = (__bf16)tile[tx * 4 + 3][c];
        *(bf16x4v*)(dst + (long long)(c0 + c) * lddst + r0 + tx * 4) = o;
    }
}

// ---------------------------------------------------------------------------
// bias rank-1 prep (exact; zeros for this input)
// ---------------------------------------------------------------------------
__global__ __launch_bounds__(256) void uvc_w(
    const float* __restrict__ Wth, const float* __restrict__ Wph,
    const float* __restrict__ bth, const float* __restrict__ bph,
    float* __restrict__ w1w2) {
    const int i = blockIdx.y;
    const int w = threadIdx.x >> 6, l = threadIdx.x & 63;
    const int c = blockIdx.x * 4 + w;
    const float* Wt = Wth + (long long)i * 262144 + (long long)c * 512;
    const float* Wp = Wph + (long long)i * 262144 + (long long)c * 512;
    const float* bt = bth + i * 512;
    const float* bp = bph + i * 512;
    float s1 = 0.f, s2 = 0.f;
#pragma unroll
    for (int e = 0; e < 8; ++e) {
        int f = l + 64 * e;
        s1 = fmaf(Wt[f], bp[f], s1);
        s2 = fmaf(Wp[f], bt[f], s2);
    }
#pragma unroll
    for (int o = 32; o > 0; o >>= 1) { s1 += __shfl_down(s1, o); s2 += __shfl_down(s2, o); }
    if (l == 0) { w1w2[i * 1024 + c] = s1; w1w2[i * 1024 + 512 + c] = s2; }
}

__global__ void cvals_k(const float* __restrict__ bth, const float* __restrict__ bph,
                        float* __restrict__ cvals) {
    const int i = blockIdx.x;
    const int l = threadIdx.x;  // 64
    float s = 0.f;
#pragma unroll
    for (int e = 0; e < 8; ++e)
        s = fmaf(bth[i * 512 + l + 64 * e], bph[i * 512 + l + 64 * e], s);
#pragma unroll
    for (int o = 32; o > 0; o >>= 1) s += __shfl_down(s, o);
    if (l == 0) cvals[i] = s;
}

__global__ __launch_bounds__(256) void uvc_x(
    const float* __restrict__ x, const float* __restrict__ w1w2,
    float* __restrict__ u, float* __restrict__ v) {
    __shared__ float wv[24][512];
    const int t = threadIdx.x;
    for (int idx = t; idx < 3072; idx += 256) {
        int j = idx >> 7, c4 = idx & 127;
        const float* src = (j < 12) ? (w1w2 + j * 1024 + c4 * 4)
                                    : (w1w2 + (j - 12) * 1024 + 512 + c4 * 4);
        *(float4*)&wv[j][c4 * 4] = *(const float4*)src;
    }
    __syncthreads();
    const int w = t >> 6, l = t & 63;
    const int row = blockIdx.x * 4 + w;
    float xv[8];
#pragma unroll
    for (int e = 0; e < 8; ++e) xv[e] = x[(long long)row * 512 + l + 64 * e];
#pragma unroll
    for (int j = 0; j < 24; ++j) {
        float p = 0.f;
#pragma unroll
        for (int e = 0; e < 8; ++e) p = fmaf(xv[e], wv[j][l + 64 * e], p);
#pragma unroll
        for (int o = 32; o > 0; o >>= 1) p += __shfl_down(p, o);
        if (l == 0) {
            if (j < 12) u[j * BS + row] = p;
            else        v[(j - 12) * BS + row] = p;
        }
    }
}

// ---------------------------------------------------------------------------
// bf16 MFMA GEMM, "nt": C[M][N] = A[M][K] * Bt[N][K]^T (f32 accum)
// 128x128 tile, BK=64, XOR-swizzled LDS, double-buffered 2-phase K-loop,
// 8 WAVES (512 threads, wave grid 4x2, 32x64 per wave) for occupancy,
// XCD-contiguous block swizzle (total blocks % 8 == 0 required).
// Batch index bz splits as bz_hi = bz/zdiv (graph), bz_lo = bz%zdiv (batch).
// MODE 1: sim epilogue: (acc+u+v+c)*scale, mask -> -inf; f32 or bf16 out (obf)
// MODE 2: bf16 out
// MODE 3: f32 out + fused LN partial stats (atomicAdd per block)
// ---------------------------------------------------------------------------
template <int MODE>
__global__ __launch_bounds__(512) void gemm_bf16(
    const __bf16* __restrict__ A, const __bf16* __restrict__ Bt, void* __restrict__ Cv,
    int lda, int ldb, int ldc, int K, int zdiv,
    long long sA_hi, long long sA, long long sB_hi, long long sB,
    long long sC_hi, long long sC,
    const float* __restrict__ uvec, const float* __restrict__ vvec,
    const float* __restrict__ cptr,
    const float4* __restrict__ posr, const int* __restrict__ OWp, float scale,
    __bf16* __restrict__ obf_out, int obf, float* __restrict__ statsraw) {

    // XCD-contiguous swizzle
    const int gx = gridDim.x, gy = gridDim.y;
    int id = blockIdx.x + gx * (blockIdx.y + gy * blockIdx.z);
    const int q = (gx * gy * gridDim.z) >> 3;
    id = (id & 7) * q + (id >> 3);
    const int bx = id % gx;
    const int rem = id / gx;
    const int by = rem % gy;
    const int bz = rem / gy;
    const int bzh = bz / zdiv, bzl = bz - bzh * zdiv;

    A += sA_hi * bzh + sA * bzl;
    Bt += sB_hi * bzh + sB * bzl;
    const int m0 = by * 128, n0 = bx * 128;

    __shared__ char lds[65536];  // 2 buffers x (A 16K | B 16K)

    const int t = threadIdx.x, l = t & 63, w = t >> 6;  // w 0..7
    const int wm = w >> 1, wn = w & 1;                  // 4x2 wave grid

    f32x4 acc[2][4] = {};

    // staging: wave w stages 16 rows of A and 16 of B (2 instrs each of 8 rows)
    // lane l -> row +(l>>3), LDS granule (l&7) gets source granule (l&7)^(row&7)
    const int g2 = (((l & 7) ^ (l >> 3)) << 4);
    const long long la2 = (long long)lda * 2, lb2 = (long long)ldb * 2;
    const char* Agp = (const char*)A + (long long)(m0 + w * 16 + (l >> 3)) * la2 + g2;
    const char* Bgp = (const char*)Bt + (long long)(n0 + w * 16 + (l >> 3)) * lb2 + g2;

    // fragment reads: row ...+fr, granule g=ks*4+qh at slot g^(row&7)
    const int fr = l & 15, qh = l >> 4, sx = l & 7;
    int offA[2][2], offB[2][4];
#pragma unroll
    for (int ks = 0; ks < 2; ++ks) {
        const int swz = (((ks << 2) | qh) ^ sx) << 4;
#pragma unroll
        for (int i = 0; i < 2; ++i)
            offA[ks][i] = (wm * 32 + i * 16 + fr) * 128 + swz;
#pragma unroll
        for (int j = 0; j < 4; ++j)
            offB[ks][j] = 16384 + (wn * 64 + j * 16 + fr) * 128 + swz;
    }

#define STAGE(kt, bufo)                                                        \
    {                                                                          \
        const long long kb = (long long)(kt) * 128;                            \
        char* lA = lds + (bufo) + w * 2048;                                    \
        char* lB = lds + (bufo) + 16384 + w * 2048;                            \
        GLOAD16(Agp + kb, lA);                                                 \
        GLOAD16(Agp + kb + 8 * la2, lA + 1024);                                \
        GLOAD16(Bgp + kb, lB);                                                 \
        GLOAD16(Bgp + kb + 8 * lb2, lB + 1024);                                \
    }

    const int KT = K >> 6;
    STAGE(0, 0);
    __syncthreads();
    for (int kt = 0; kt < KT; ++kt) {
        const int cur = (kt & 1) << 15;
        if (kt + 1 < KT) STAGE(kt + 1, cur ^ 32768);
#pragma unroll
        for (int ks = 0; ks < 2; ++ks) {
            bf16x8 af[2], bfr[4];
#pragma unroll
            for (int i = 0; i < 2; ++i) af[i] = *(const bf16x8*)(lds + cur + offA[ks][i]);
#pragma unroll
            for (int j = 0; j < 4; ++j) bfr[j] = *(const bf16x8*)(lds + cur + offB[ks][j]);
#pragma unroll
            for (int i = 0; i < 2; ++i)
#pragma unroll
                for (int j = 0; j < 4; ++j)
                    acc[i][j] = __builtin_amdgcn_mfma_f32_16x16x32_bf16(
                        af[i], bfr[j], acc[i][j], 0, 0, 0);
        }
        __syncthreads();
    }
#undef STAGE

    // C/D frag: col = n0+wn*64+j*16+(l&15), row = m0+wm*32+i*16+(l>>4)*4+r
    const int crow0 = m0 + wm * 32 + (l >> 4) * 4;
    const int ccol0 = n0 + wn * 64 + fr;

    if (MODE == 1) {
        const float4* pr = posr + bzl * Ss;
        const float* uv = uvec + bzl * Ss;
        const float* vv = vvec + bzl * Ss;
        const float cadd = cptr[0];
        const float thr = 0.2f * (float)(*OWp);
        float4 pm[4];
        float vj[4];
#pragma unroll
        for (int j = 0; j < 4; ++j) {
            pm[j] = pr[ccol0 + j * 16];
            vj[j] = vv[ccol0 + j * 16];
        }
        float* Cf = (float*)Cv + sC * bzl;
        __bf16* Cb = obf_out + sC * bzl;
#pragma unroll
        for (int i = 0; i < 2; ++i)
#pragma unroll
            for (int r = 0; r < 4; ++r) {
                int row = crow0 + i * 16 + r;
                float4 pn = pr[row];
                float un = uv[row];
#pragma unroll
                for (int j = 0; j < 4; ++j) {
                    float e = fmaf(pn.y, pm[j].y, pn.x * pm[j].x);
                    float d2 = __fadd_rn(__fsub_rn(pn.z, __fmul_rn(2.0f, e)), pm[j].z);
                    float dist = sqrtf(fmaxf(d2, 0.0f));
                    float v = (acc[i][j][r] + un + vj[j] + cadd) * scale;
                    float ov = (dist > thr) ? -INFINITY : v;
                    if (obf) Cb[(long long)row * ldc + ccol0 + j * 16] = (__bf16)ov;
                    else     Cf[(long long)row * ldc + ccol0 + j * 16] = ov;
                }
            }
    } else if (MODE == 2) {
        __bf16* C = (__bf16*)Cv + sC_hi * bzh + sC * bzl;
#pragma unroll
        for (int j = 0; j < 4; ++j)
#pragma unroll
            for (int i = 0; i < 2; ++i)
#pragma unroll
                for (int r = 0; r < 4; ++r) {
                    int row = crow0 + i * 16 + r;
                    C[(long long)row * ldc + ccol0 + j * 16] = (__bf16)acc[i][j][r];
                }
    } else {
        float* C = (float*)Cv + sC_hi * bzh + sC * bzl;
        float s = 0.f, ss = 0.f;
#pragma unroll
        for (int j = 0; j < 4; ++j)
#pragma unroll
            for (int i = 0; i < 2; ++i)
#pragma unroll
                for (int r = 0; r < 4; ++r) {
                    int row = crow0 + i * 16 + r;
                    float ov = acc[i][j][r];
                    C[(long long)row * ldc + ccol0 + j * 16] = ov;
                    s += ov;
                    ss = fmaf(ov, ov, ss);
                }
#pragma unroll
        for (int o = 32; o > 0; o >>= 1) {
            s += __shfl_down(s, o);
            ss += __shfl_down(ss, o);
        }
        float* redf = (float*)lds;
        if (l == 0) { redf[w * 2] = s; redf[w * 2 + 1] = ss; }
        __syncthreads();
        if (t == 0) {
            float S = 0.f, SS = 0.f;
#pragma unroll
            for (int ww = 0; ww < 8; ++ww) { S += redf[ww * 2]; SS += redf[ww * 2 + 1]; }
            atomicAdd(&statsraw[bzl * 2], S);
            atomicAdd(&statsraw[bzl * 2 + 1], SS);
        }
    }
}

// ---------------------------------------------------------------------------
// Row softmax, rows of 1280. INBF=1: bf16 in, bf16 out. INBF=0: f32 in,
// bf16 out + f32 in-place (final relation output).
// ---------------------------------------------------------------------------
template <int INBF>
__global__ __launch_bounds__(256) void softmax_rows(
    const __bf16* __restrict__ inbf, float* __restrict__ f32io,
    __bf16* __restrict__ relbf) {
    const int row = blockIdx.x;
    __shared__ float buf[Ss];
    __shared__ float wred[4];
    const int t = threadIdx.x;

    float m = -INFINITY;
    if (INBF) {
        const __bf16* p = inbf + (long long)row * Ss;
        for (int j = t; j < Ss; j += 256) {
            float v = (float)p[j];
            buf[j] = v;
            m = fmaxf(m, v);
        }
    } else {
        const float* p = f32io + (long long)row * Ss;
        for (int j = t; j < Ss; j += 256) {
            float v = p[j];
            buf[j] = v;
            m = fmaxf(m, v);
        }
    }
#pragma unroll
    for (int o = 32; o > 0; o >>= 1) m = fmaxf(m, __shfl_down(m, o));
    if ((t & 63) == 0) wred[t >> 6] = m;
    __syncthreads();
    const float m4 = fmaxf(fmaxf(wred[0], wred[1]), fmaxf(wred[2], wred[3]));
    __syncthreads();

    float s = 0.0f;
    for (int j = t; j < Ss; j += 256) {
        float e = expf(buf[j] - m4);
        buf[j] = e;
        s += e;
    }
#pragma unroll
    for (int o = 32; o > 0; o >>= 1) s += __shfl_down(s, o);
    if ((t & 63) == 0) wred[t >> 6] = s;
    __syncthreads();
    const float total = wred[0] + wred[1] + wred[2] + wred[3];
    const float inv = 1.0f / total;
    __bf16* qo = relbf + (long long)row * Ss;
    float* po = f32io + (long long)row * Ss;
    for (int j = t; j < Ss; j += 256) {
        float v = buf[j] * inv;
        qo[j] = (__bf16)v;
        if (!INBF) po[j] = v;
    }
}

// ---------------------------------------------------------------------------
__global__ void stats_final(float* __restrict__ raw, float2* __restrict__ stats) {
    const int b = threadIdx.x;
    if (b < Bb) {
        float S = raw[b * 2], SS = raw[b * 2 + 1];
        const float invn = 1.0f / (float)SC;
        float mu = S * invn;
        float var = SS * invn - mu * mu;
        stats[b] = make_float2(mu, 1.0f / sqrtf(var + 1e-5f));
        raw[b * 2] = 0.f;
        raw[b * 2 + 1] = 0.f;
    }
}

// ---------------------------------------------------------------------------
__global__ __launch_bounds__(256) void ln_relu_acc(
    const float* __restrict__ agg, const float2* __restrict__ stats,
    const float* __restrict__ lnsc, const float* __restrict__ lnbi,
    float* __restrict__ out, int first) {
    for (int idx = blockIdx.x * 256 + threadIdx.x; idx < (Bb * SC) / 4;
         idx += gridDim.x * 256) {
        int b = idx / (SC / 4);
        int j = idx - b * (SC / 4);
        float2 st = stats[b];
        float4 a = ((const float4*)agg)[idx];
        float4 sc = ((const float4*)lnsc)[j];
        float4 bi = ((const float4*)lnbi)[j];
        float4 o;
        o.x = fmaxf((a.x - st.x) * st.y * sc.x + bi.x, 0.f);
        o.y = fmaxf((a.y - st.x) * st.y * sc.y + bi.y, 0.f);
        o.z = fmaxf((a.z - st.x) * st.y * sc.z + bi.z, 0.f);
        o.w = fmaxf((a.w - st.x) * st.y * sc.w + bi.w, 0.f);
        float4* op = (float4*)out + idx;
        if (!first) {
            float4 pv = *op;
            o.x += pv.x; o.y += pv.y; o.z += pv.z; o.w += pv.w;
        }
        *op = o;
    }
}

// ---------------------------------------------------------------------------
extern "C" void kernel_launch(void* const* d_in, const int* in_sizes, int n_in,
                              void* d_out, int out_size, void* d_ws, size_t ws_size,
                              hipStream_t stream) {
    const float* x        = (const float*)d_in[0];
    const float* box      = (const float*)d_in[1];
    const float* W_theta  = (const float*)d_in[2];
    const float* b_theta  = (const float*)d_in[3];
    const float* W_phi    = (const float*)d_in[4];
    const float* b_phi    = (const float*)d_in[5];
    const float* W_gcn    = (const float*)d_in[6];
    const float* ln_scale = (const float*)d_in[7];
    const float* ln_bias  = (const float*)d_in[8];
    const int*   OWp      = (const int*)d_in[10];

    float* out = (float*)d_out;            // [8,1280,512]
    float* rel_f32 = out + OUT0;           // [8,1280,1280] (output 1 region)
    __bf16* simbf = (__bf16*)rel_f32;      // bf16 sim scratch (iters 0..10)

    char* ws = (char*)d_ws;
    float4* posr   = (float4*)(ws + 0);                 //   163840
    __bf16* x_bf   = (__bf16*)(ws + 163840);            // 10485760 [10240][512]
    __bf16* Wgt    = (__bf16*)(ws + 10649600);          //  6291456 [12][512][512]
    __bf16* GiT    = (__bf16*)(ws + 16941056);          //  6291456 [12][512][512]
    float*  w1w2   = (float*)(ws + 23232512);           //    49152
    float*  cvals  = (float*)(ws + 23281664);           //      256
    float*  u      = (float*)(ws + 23281920);           //   491520 [12][10240]
    float*  v      = (float*)(ws + 23773440);           //   491520
    float*  sraw   = (float*)(ws + 24264960);           //       64
    float2* stats  = (float2*)(ws + 24265216);          //       64
    __bf16* ybuf   = (__bf16*)(ws + 24265728);          // 10485760 [10240][512]
    __bf16* z_all  = (__bf16*)(ws + 34751488);          // 125829120 [12][8][512][1280]
    __bf16* relbf  = (__bf16*)(ws + 160580608);         // 26214400 [8][1280][1280]
    float*  aggF   = (float*)(ws + 186795008);          // 20971520 [10240][512] f32
    // prep-only aliases (inside aggF region; dead once loop starts)
    __bf16* Wth_bf = (__bf16*)(ws + 186795008);         //  6291456
    __bf16* Wph_bf = (__bf16*)(ws + 193086464);         //  6291456

    hipMemsetAsync(sraw, 0, 64, stream);

    // ---- one-time prep ----
    compute_pos<<<dim3(40), dim3(256), 0, stream>>>(box, posr);
    cvt_bf16<<<dim3(2048), dim3(256), 0, stream>>>(x, x_bf, OUT0 / 4);
    cvt_bf16<<<dim3(2048), dim3(256), 0, stream>>>(W_theta, Wth_bf, 786432);
    cvt_bf16<<<dim3(2048), dim3(256), 0, stream>>>(W_phi, Wph_bf, 786432);
    transpose_cvt<<<dim3(8, 8, 12), dim3(256), 0, stream>>>(
        W_gcn, Wgt, Cc, Cc, (long long)Cc * Cc, (long long)Cc * Cc);
    // GiT[i][d][c] = sum_f Wphi[d][f] * Wtheta[c][f]
    gemm_bf16<2><<<dim3(4, 4, 12), dim3(512), 0, stream>>>(
        Wph_bf, Wth_bf, GiT, Cc, Cc, Cc, Cc, 1,
        262144, 0, 262144, 0, 262144, 0,
        nullptr, nullptr, nullptr, nullptr, nullptr, 0.f, nullptr, 0, nullptr);
    // bias rank-1 terms (exact; zeros for this input)
    uvc_w<<<dim3(128, 12), dim3(256), 0, stream>>>(W_theta, W_phi, b_theta, b_phi, w1w2);
    cvals_k<<<dim3(12), dim3(64), 0, stream>>>(b_theta, b_phi, cvals);
    uvc_x<<<dim3(2560), dim3(256), 0, stream>>>(x, w1w2, u, v);
    // z_all[i][b][c][s] = sum_f Wgt_i[c][f] * x_b[s][f]   (batched over all 12 graphs)
    gemm_bf16<2><<<dim3(10, 4, 96), dim3(512), 0, stream>>>(
        Wgt, x_bf, z_all, Cc, Cc, Ss, Cc, 8,
        262144, 0, 0, (long long)SC, (long long)Bb * Cc * Ss, (long long)Cc * Ss,
        nullptr, nullptr, nullptr, nullptr, nullptr, 0.f, nullptr, 0, nullptr);

    const float inv_sqrt = 0.044194173824159216f;  // 1/sqrt(512)

    for (int i = 0; i < NG; ++i) {
        const __bf16* Gi  = GiT + (long long)i * Cc * Cc;
        const __bf16* Zi  = z_all + (long long)i * Bb * Cc * Ss;
        const int last = (i == NG - 1);
        // y = x @ G_i -> bf16 [10240][512]
        gemm_bf16<2><<<dim3(4, 80, 1), dim3(512), 0, stream>>>(
            x_bf, Gi, ybuf, Cc, Cc, Cc, Cc, 1,
            0, 0, 0, 0, 0, 0,
            nullptr, nullptr, nullptr, nullptr, nullptr, 0.f, nullptr, 0, nullptr);
        // sim = (y @ x^T + u + v + c)*scale, masked; bf16 (iters 0..10) or f32 (last)
        gemm_bf16<1><<<dim3(10, 10, 8), dim3(512), 0, stream>>>(
            ybuf, x_bf, rel_f32, Cc, Cc, Ss, Cc, 8,
            0, (long long)Ss * Cc, 0, (long long)Ss * Cc, 0, (long long)Ss * Ss,
            u + (long long)i * BS, v + (long long)i * BS, cvals + i,
            posr, OWp, inv_sqrt, simbf, last ? 0 : 1, nullptr);
        // softmax rows -> relbf (+ f32 in place on last)
        if (last)
            softmax_rows<0><<<dim3(BS), dim3(256), 0, stream>>>(nullptr, rel_f32, relbf);
        else
            softmax_rows<1><<<dim3(BS), dim3(256), 0, stream>>>(simbf, nullptr, relbf);
        // agg = P @ z_i -> f32 (+ fused LN partial stats)
        gemm_bf16<3><<<dim3(4, 10, 8), dim3(512), 0, stream>>>(
            relbf, Zi, aggF, Ss, Ss, Cc, Ss, 8,
            0, (long long)Ss * Ss, 0, (long long)Cc * Ss, 0, (long long)SC,
            nullptr, nullptr, nullptr, nullptr, nullptr, 0.f, nullptr, 0, sraw);
        // finalize stats (and reset raw accumulators)
        stats_final<<<dim3(1), dim3(64), 0, stream>>>(sraw, stats);
        // out (+)= relu(LN(agg))
        ln_relu_acc<<<dim3(2048), dim3(256), 0, stream>>>(
            aggF, stats, ln_scale + (long long)i * SC, ln_bias + (long long)i * SC,
            out, i == 0 ? 1 : 0);
    }
}

// Round 8
// 1425.202 us; speedup vs baseline: 6.3838x; 1.1529x over previous
//
#include <hip/hip_runtime.h>
#include <math.h>

// Problem constants
#define NG   12
#define Bb   8
#define Ss   1280
#define Cc   512
#define BS   10240            // B*S
#define SC   655360           // S*C per batch
#define OUT0 5242880          // B*S*C floats (output 0)

typedef __bf16 bf16x8 __attribute__((ext_vector_type(8)));
typedef __bf16 bf16x4v __attribute__((ext_vector_type(4)));
typedef float  f32x4  __attribute__((ext_vector_type(4)));

#define GLOAD16(gp, lp)                                                        \
    __builtin_amdgcn_global_load_lds(                                          \
        (const __attribute__((address_space(1))) void*)(gp),                   \
        (__attribute__((address_space(3))) void*)(lp), 16, 0, 0)

// ---------------------------------------------------------------------------
__global__ __launch_bounds__(256) void compute_pos(const float* __restrict__ box,
                                                   float4* __restrict__ posr) {
    int i = blockIdx.x * 256 + threadIdx.x;
    if (i < BS) {
        float x0 = box[i * 4 + 0], y0 = box[i * 4 + 1];
        float x1 = box[i * 4 + 2], y1 = box[i * 4 + 3];
        float cx = (x0 + x1) * 0.5f;
        float cy = (y0 + y1) * 0.5f;
        float px = __fmul_rn(cx, cx);
        float py = __fmul_rn(cy, cy);
        posr[i] = make_float4(cx, cy, __fadd_rn(px, py), 0.0f);
    }
}

// ---------------------------------------------------------------------------
__global__ __launch_bounds__(256) void cvt_bf16(const float* __restrict__ src,
                                                __bf16* __restrict__ dst, int n4) {
    for (int i = blockIdx.x * 256 + threadIdx.x; i < n4; i += gridDim.x * 256) {
        float4 v = ((const float4*)src)[i];
        bf16x4v o;
        o[0] = (__bf16)v.x; o[1] = (__bf16)v.y; o[2] = (__bf16)v.z; o[3] = (__bf16)v.w;
        *(bf16x4v*)(dst + i * 4) = o;
    }
}

// ---------------------------------------------------------------------------
// Tiled transpose + convert: dst[c][r] (bf16) = src[r][c] (f32). 64x64 tiles.
// ---------------------------------------------------------------------------
__global__ __launch_bounds__(256) void transpose_cvt(
    const float* __restrict__ src, __bf16* __restrict__ dst,
    int ldsrc, int lddst, long long sSrc, long long sDst) {
    src += sSrc * blockIdx.z;
    dst += sDst * blockIdx.z;
    __shared__ float tile[64][65];
    const int t = threadIdx.x, tx = t & 15, ty = t >> 4;
    const int r0 = blockIdx.x * 64, c0 = blockIdx.y * 64;
#pragma unroll
    for (int rr = 0; rr < 4; ++rr) {
        int r = ty + rr * 16;
        float4 v = *(const float4*)(src + (long long)(r0 + r) * ldsrc + c0 + tx * 4);
        tile[r][tx * 4 + 0] = v.x;
        tile[r][tx * 4 + 1] = v.y;
        tile[r][tx * 4 + 2] = v.z;
        tile[r][tx * 4 + 3] = v.w;
    }
    __syncthreads();
#pragma unroll
    for (int rr = 0; rr < 4; ++rr) {
        int c = ty + rr * 16;
        bf16x4v o;
        o[0] = (__bf16)tile[tx * 4 + 0][c];
        o[1] = (__bf16)tile[tx * 4 + 1][c];
        o[2] = (__bf16)tile[tx * 4 + 2][c];
        o[3] = (__bf16)tile[tx * 4 + 3][c];
        *(bf16x4v*)(dst + (long long)(c0 + c) * lddst + r0 + tx * 4) = o;
    }
}

// ---------------------------------------------------------------------------
// bias rank-1 prep (exact; zeros for this input)
// ---------------------------------------------------------------------------
__global__ __launch_bounds__(256) void uvc_w(
    const float* __restrict__ Wth, const float* __restrict__ Wph,
    const float* __restrict__ bth, const float* __restrict__ bph,
    float* __restrict__ w1w2) {
    const int i = blockIdx.y;
    const int w = threadIdx.x >> 6, l = threadIdx.x & 63;
    const int c = blockIdx.x * 4 + w;
    const float* Wt = Wth + (long long)i * 262144 + (long long)c * 512;
    const float* Wp = Wph + (long long)i * 262144 + (long long)c * 512;
    const float* bt = bth + i * 512;
    const float* bp = bph + i * 512;
    float s1 = 0.f, s2 = 0.f;
#pragma unroll
    for (int e = 0; e < 8; ++e) {
        int f = l + 64 * e;
        s1 = fmaf(Wt[f], bp[f], s1);
        s2 = fmaf(Wp[f], bt[f], s2);
    }
#pragma unroll
    for (int o = 32; o > 0; o >>= 1) { s1 += __shfl_down(s1, o); s2 += __shfl_down(s2, o); }
    if (l == 0) { w1w2[i * 1024 + c] = s1; w1w2[i * 1024 + 512 + c] = s2; }
}

__global__ void cvals_k(const float* __restrict__ bth, const float* __restrict__ bph,
                        float* __restrict__ cvals) {
    const int i = blockIdx.x;
    const int l = threadIdx.x;  // 64
    float s = 0.f;
#pragma unroll
    for (int e = 0; e < 8; ++e)
        s = fmaf(bth[i * 512 + l + 64 * e], bph[i * 512 + l + 64 * e], s);
#pragma unroll
    for (int o = 32; o > 0; o >>= 1) s += __shfl_down(s, o);
    if (l == 0) cvals[i] = s;
}

__global__ __launch_bounds__(256) void uvc_x(
    const float* __restrict__ x, const float* __restrict__ w1w2,
    float* __restrict__ u, float* __restrict__ v) {
    __shared__ float wv[24][512];
    const int t = threadIdx.x;
    for (int idx = t; idx < 3072; idx += 256) {
        int j = idx >> 7, c4 = idx & 127;
        const float* src = (j < 12) ? (w1w2 + j * 1024 + c4 * 4)
                                    : (w1w2 + (j - 12) * 1024 + 512 + c4 * 4);
        *(float4*)&wv[j][c4 * 4] = *(const float4*)src;
    }
    __syncthreads();
    const int w = t >> 6, l = t & 63;
    const int row = blockIdx.x * 4 + w;
    float xv[8];
#pragma unroll
    for (int e = 0; e < 8; ++e) xv[e] = x[(long long)row * 512 + l + 64 * e];
#pragma unroll
    for (int j = 0; j < 24; ++j) {
        float p = 0.f;
#pragma unroll
        for (int e = 0; e < 8; ++e) p = fmaf(xv[e], wv[j][l + 64 * e], p);
#pragma unroll
        for (int o = 32; o > 0; o >>= 1) p += __shfl_down(p, o);
        if (l == 0) {
            if (j < 12) u[j * BS + row] = p;
            else        v[(j - 12) * BS + row] = p;
        }
    }
}

// ---------------------------------------------------------------------------
// bf16 MFMA GEMM, "nt": C[M][N] = A[M][K] * Bt[N][K]^T (f32 accum)
// 128x128 tile, BK=64, XOR-swizzled LDS, double-buffered 2-phase K-loop,
// 8 waves (512 threads, wave grid 4x2, 32x64 per wave),
// XCD-contiguous block swizzle (total blocks % 8 == 0 required).
// bz splits: bzh = bz/zdiv (graph slot), bzl = bz%zdiv (batch).
// MODE 1: sim: (acc+u+v+c)*scale, mask -> -inf; bf16 out if bzh<nbf else f32
// MODE 2: bf16 out
// MODE 3: f32 out + fused LN partial stats (atomicAdd per (bzh,bzl))
// ---------------------------------------------------------------------------
template <int MODE>
__global__ __launch_bounds__(512) void gemm_bf16(
    const __bf16* __restrict__ A, const __bf16* __restrict__ Bt, void* __restrict__ Cv,
    int lda, int ldb, int ldc, int K, int zdiv,
    long long sA_hi, long long sA, long long sB_hi, long long sB,
    long long sC_hi, long long sC,
    const float* __restrict__ uvec, const float* __restrict__ vvec,
    const float* __restrict__ cptr,
    const float4* __restrict__ posr, const int* __restrict__ OWp, float scale,
    __bf16* __restrict__ obf_out, long long sOb, int nbf,
    float* __restrict__ statsraw) {

    // XCD-contiguous swizzle
    const int gx = gridDim.x, gy = gridDim.y;
    int id = blockIdx.x + gx * (blockIdx.y + gy * blockIdx.z);
    const int q = (gx * gy * gridDim.z) >> 3;
    id = (id & 7) * q + (id >> 3);
    const int bx = id % gx;
    const int rem = id / gx;
    const int by = rem % gy;
    const int bz = rem / gy;
    const int bzh = bz / zdiv, bzl = bz - bzh * zdiv;

    A += sA_hi * bzh + sA * bzl;
    Bt += sB_hi * bzh + sB * bzl;
    const int m0 = by * 128, n0 = bx * 128;

    __shared__ char lds[65536];  // 2 buffers x (A 16K | B 16K)

    const int t = threadIdx.x, l = t & 63, w = t >> 6;  // w 0..7
    const int wm = w >> 1, wn = w & 1;                  // 4x2 wave grid

    f32x4 acc[2][4] = {};

    // staging: wave w stages 16 rows of A and B; lane l -> row +(l>>3),
    // LDS granule (l&7) gets source granule (l&7)^(row&7)
    const int g2 = (((l & 7) ^ (l >> 3)) << 4);
    const long long la2 = (long long)lda * 2, lb2 = (long long)ldb * 2;
    const char* Agp = (const char*)A + (long long)(m0 + w * 16 + (l >> 3)) * la2 + g2;
    const char* Bgp = (const char*)Bt + (long long)(n0 + w * 16 + (l >> 3)) * lb2 + g2;

    // fragment reads: row ...+fr, granule g=ks*4+qh at slot g^(row&7)
    const int fr = l & 15, qh = l >> 4, sx = l & 7;
    int offA[2][2], offB[2][4];
#pragma unroll
    for (int ks = 0; ks < 2; ++ks) {
        const int swz = (((ks << 2) | qh) ^ sx) << 4;
#pragma unroll
        for (int i = 0; i < 2; ++i)
            offA[ks][i] = (wm * 32 + i * 16 + fr) * 128 + swz;
#pragma unroll
        for (int j = 0; j < 4; ++j)
            offB[ks][j] = 16384 + (wn * 64 + j * 16 + fr) * 128 + swz;
    }

#define STAGE(kt, bufo)                                                        \
    {                                                                          \
        const long long kb = (long long)(kt) * 128;                            \
        char* lA = lds + (bufo) + w * 2048;                                    \
        char* lB = lds + (bufo) + 16384 + w * 2048;                            \
        GLOAD16(Agp + kb, lA);                                                 \
        GLOAD16(Agp + kb + 8 * la2, lA + 1024);                                \
        GLOAD16(Bgp + kb, lB);                                                 \
        GLOAD16(Bgp + kb + 8 * lb2, lB + 1024);                                \
    }

    const int KT = K >> 6;
    STAGE(0, 0);
    __syncthreads();
    for (int kt = 0; kt < KT; ++kt) {
        const int cur = (kt & 1) << 15;
        if (kt + 1 < KT) STAGE(kt + 1, cur ^ 32768);
#pragma unroll
        for (int ks = 0; ks < 2; ++ks) {
            bf16x8 af[2], bfr[4];
#pragma unroll
            for (int i = 0; i < 2; ++i) af[i] = *(const bf16x8*)(lds + cur + offA[ks][i]);
#pragma unroll
            for (int j = 0; j < 4; ++j) bfr[j] = *(const bf16x8*)(lds + cur + offB[ks][j]);
#pragma unroll
            for (int i = 0; i < 2; ++i)
#pragma unroll
                for (int j = 0; j < 4; ++j)
                    acc[i][j] = __builtin_amdgcn_mfma_f32_16x16x32_bf16(
                        af[i], bfr[j], acc[i][j], 0, 0, 0);
        }
        __syncthreads();
    }
#undef STAGE

    // C/D frag: col = n0+wn*64+j*16+(l&15), row = m0+wm*32+i*16+(l>>4)*4+r
    const int crow0 = m0 + wm * 32 + (l >> 4) * 4;
    const int ccol0 = n0 + wn * 64 + fr;

    if (MODE == 1) {
        const float4* pr = posr + bzl * Ss;
        const float* uv = uvec + (long long)bzh * BS + bzl * Ss;
        const float* vv = vvec + (long long)bzh * BS + bzl * Ss;
        const float cadd = cptr[bzh];
        const float thr = 0.2f * (float)(*OWp);
        float4 pm[4];
        float vj[4];
#pragma unroll
        for (int j = 0; j < 4; ++j) {
            pm[j] = pr[ccol0 + j * 16];
            vj[j] = vv[ccol0 + j * 16];
        }
        float* Cf = (float*)Cv + sC * bzl;
        __bf16* Cb = obf_out + sOb * bzh + sC * bzl;
        const int as_bf = (bzh < nbf);
#pragma unroll
        for (int i = 0; i < 2; ++i)
#pragma unroll
            for (int r = 0; r < 4; ++r) {
                int row = crow0 + i * 16 + r;
                float4 pn = pr[row];
                float un = uv[row];
#pragma unroll
                for (int j = 0; j < 4; ++j) {
                    float e = fmaf(pn.y, pm[j].y, pn.x * pm[j].x);
                    float d2 = __fadd_rn(__fsub_rn(pn.z, __fmul_rn(2.0f, e)), pm[j].z);
                    float dist = sqrtf(fmaxf(d2, 0.0f));
                    float v = (acc[i][j][r] + un + vj[j] + cadd) * scale;
                    float ov = (dist > thr) ? -INFINITY : v;
                    if (as_bf) Cb[(long long)row * ldc + ccol0 + j * 16] = (__bf16)ov;
                    else       Cf[(long long)row * ldc + ccol0 + j * 16] = ov;
                }
            }
    } else if (MODE == 2) {
        __bf16* C = (__bf16*)Cv + sC_hi * bzh + sC * bzl;
#pragma unroll
        for (int j = 0; j < 4; ++j)
#pragma unroll
            for (int i = 0; i < 2; ++i)
#pragma unroll
                for (int r = 0; r < 4; ++r) {
                    int row = crow0 + i * 16 + r;
                    C[(long long)row * ldc + ccol0 + j * 16] = (__bf16)acc[i][j][r];
                }
    } else {
        float* C = (float*)Cv + sC_hi * bzh + sC * bzl;
        float s = 0.f, ss = 0.f;
#pragma unroll
        for (int j = 0; j < 4; ++j)
#pragma unroll
            for (int i = 0; i < 2; ++i)
#pragma unroll
                for (int r = 0; r < 4; ++r) {
                    int row = crow0 + i * 16 + r;
                    float ov = acc[i][j][r];
                    C[(long long)row * ldc + ccol0 + j * 16] = ov;
                    s += ov;
                    ss = fmaf(ov, ov, ss);
                }
#pragma unroll
        for (int o = 32; o > 0; o >>= 1) {
            s += __shfl_down(s, o);
            ss += __shfl_down(ss, o);
        }
        float* redf = (float*)lds;
        if (l == 0) { redf[w * 2] = s; redf[w * 2 + 1] = ss; }
        __syncthreads();
        if (t == 0) {
            float S = 0.f, SS = 0.f;
#pragma unroll
            for (int ww = 0; ww < 8; ++ww) { S += redf[ww * 2]; SS += redf[ww * 2 + 1]; }
            atomicAdd(&statsraw[(bzh * zdiv + bzl) * 2], S);
            atomicAdd(&statsraw[(bzh * zdiv + bzl) * 2 + 1], SS);
        }
    }
}

// ---------------------------------------------------------------------------
// Row softmax, rows of 1280. INBF=1: bf16 in, bf16 out. INBF=0: f32 in,
// bf16 out + f32 in-place (final relation output).
// ---------------------------------------------------------------------------
template <int INBF>
__global__ __launch_bounds__(256) void softmax_rows(
    const __bf16* __restrict__ inbf, float* __restrict__ f32io,
    __bf16* __restrict__ relbf) {
    const int row = blockIdx.x;
    __shared__ float buf[Ss];
    __shared__ float wred[4];
    const int t = threadIdx.x;

    float m = -INFINITY;
    if (INBF) {
        const __bf16* p = inbf + (long long)row * Ss;
        for (int j = t; j < Ss; j += 256) {
            float v = (float)p[j];
            buf[j] = v;
            m = fmaxf(m, v);
        }
    } else {
        const float* p = f32io + (long long)row * Ss;
        for (int j = t; j < Ss; j += 256) {
            float v = p[j];
            buf[j] = v;
            m = fmaxf(m, v);
        }
    }
#pragma unroll
    for (int o = 32; o > 0; o >>= 1) m = fmaxf(m, __shfl_down(m, o));
    if ((t & 63) == 0) wred[t >> 6] = m;
    __syncthreads();
    const float m4 = fmaxf(fmaxf(wred[0], wred[1]), fmaxf(wred[2], wred[3]));
    __syncthreads();

    float s = 0.0f;
    for (int j = t; j < Ss; j += 256) {
        float e = expf(buf[j] - m4);
        buf[j] = e;
        s += e;
    }
#pragma unroll
    for (int o = 32; o > 0; o >>= 1) s += __shfl_down(s, o);
    if ((t & 63) == 0) wred[t >> 6] = s;
    __syncthreads();
    const float total = wred[0] + wred[1] + wred[2] + wred[3];
    const float inv = 1.0f / total;
    __bf16* qo = relbf + (long long)row * Ss;
    float* po = f32io + (long long)row * Ss;
    for (int j = t; j < Ss; j += 256) {
        float v = buf[j] * inv;
        qo[j] = (__bf16)v;
        if (!INBF) po[j] = v;
    }
}

// ---------------------------------------------------------------------------
// finalize 16 (graph-slot, batch) LN stats; reset raw accumulators
// ---------------------------------------------------------------------------
__global__ void stats_final(float* __restrict__ raw, float2* __restrict__ stats) {
    const int b = threadIdx.x;
    if (b < 16) {
        float S = raw[b * 2], SS = raw[b * 2 + 1];
        const float invn = 1.0f / (float)SC;
        float mu = S * invn;
        float var = SS * invn - mu * mu;
        stats[b] = make_float2(mu, 1.0f / sqrtf(var + 1e-5f));
        raw[b * 2] = 0.f;
        raw[b * 2 + 1] = 0.f;
    }
}

// ---------------------------------------------------------------------------
// out (+)= relu(LN(agg_g0)) + relu(LN(agg_g1))  (pair)
// ---------------------------------------------------------------------------
__global__ __launch_bounds__(256) void ln_relu2(
    const float* __restrict__ agg, const float2* __restrict__ stats,
    const float* __restrict__ lnsc, const float* __restrict__ lnbi,
    float* __restrict__ out, int first) {
    for (int idx = blockIdx.x * 256 + threadIdx.x; idx < OUT0 / 4;
         idx += gridDim.x * 256) {
        int b = idx / (SC / 4);
        int j = idx - b * (SC / 4);
        float2 s0 = stats[b], s1 = stats[8 + b];
        float4 a0 = ((const float4*)agg)[idx];
        float4 a1 = ((const float4*)agg)[idx + OUT0 / 4];
        float4 c0 = ((const float4*)lnsc)[j];
        float4 c1 = ((const float4*)(lnsc + SC))[j];
        float4 bi0 = ((const float4*)lnbi)[j];
        float4 bi1 = ((const float4*)(lnbi + SC))[j];
        float4 o;
        o.x = fmaxf((a0.x - s0.x) * s0.y * c0.x + bi0.x, 0.f)
            + fmaxf((a1.x - s1.x) * s1.y * c1.x + bi1.x, 0.f);
        o.y = fmaxf((a0.y - s0.x) * s0.y * c0.y + bi0.y, 0.f)
            + fmaxf((a1.y - s1.x) * s1.y * c1.y + bi1.y, 0.f);
        o.z = fmaxf((a0.z - s0.x) * s0.y * c0.z + bi0.z, 0.f)
            + fmaxf((a1.z - s1.x) * s1.y * c1.z + bi1.z, 0.f);
        o.w = fmaxf((a0.w - s0.x) * s0.y * c0.w + bi0.w, 0.f)
            + fmaxf((a1.w - s1.x) * s1.y * c1.w + bi1.w, 0.f);
        float4* op = (float4*)out + idx;
        if (!first) {
            float4 pv = *op;
            o.x += pv.x; o.y += pv.y; o.z += pv.z; o.w += pv.w;
        }
        *op = o;
    }
}

// ---------------------------------------------------------------------------
extern "C" void kernel_launch(void* const* d_in, const int* in_sizes, int n_in,
                              void* d_out, int out_size, void* d_ws, size_t ws_size,
                              hipStream_t stream) {
    const float* x        = (const float*)d_in[0];
    const float* box      = (const float*)d_in[1];
    const float* W_theta  = (const float*)d_in[2];
    const float* b_theta  = (const float*)d_in[3];
    const float* W_phi    = (const float*)d_in[4];
    const float* b_phi    = (const float*)d_in[5];
    const float* W_gcn    = (const float*)d_in[6];
    const float* ln_scale = (const float*)d_in[7];
    const float* ln_bias  = (const float*)d_in[8];
    const int*   OWp      = (const int*)d_in[10];

    float* out = (float*)d_out;            // [8,1280,512]
    float* rel_f32 = out + OUT0;           // [8,1280,1280] (output 1 region)
    __bf16* simbf = (__bf16*)rel_f32;      // bf16 sim pair scratch (non-last groups)

    char* ws = (char*)d_ws;
    float4* posr   = (float4*)(ws + 0);                 //   163840
    __bf16* x_bf   = (__bf16*)(ws + 163840);            // 10485760 [10240][512]
    __bf16* Wgt    = (__bf16*)(ws + 10649600);          //  6291456 [12][512][512]
    __bf16* GiT    = (__bf16*)(ws + 16941056);          //  6291456 [12][512][512]
    float*  w1w2   = (float*)(ws + 23232512);           //    49152
    float*  cvals  = (float*)(ws + 23281664);           //      256
    float*  u      = (float*)(ws + 23281920);           //   491520 [12][10240]
    float*  v      = (float*)(ws + 23773440);           //   491520
    float*  sraw   = (float*)(ws + 24264960);           //      128 (16 pairs)
    float2* stats  = (float2*)(ws + 24265088);          //      128
    __bf16* ybuf   = (__bf16*)(ws + 24265216);          // 20971520 [2][10240][512]
    __bf16* z_all  = (__bf16*)(ws + 45236736);          // 125829120 [12][8][512][1280]
    __bf16* relbf  = (__bf16*)(ws + 171065856);         // 52428800 [2][8][1280][1280]
    float*  aggF   = (float*)(ws + 223494656);          // 41943040 [2][10240][512] f32
    // prep-only aliases (inside aggF region; dead once loop starts)
    __bf16* Wth_bf = (__bf16*)(ws + 223494656);         //  6291456
    __bf16* Wph_bf = (__bf16*)(ws + 229786112);         //  6291456

    hipMemsetAsync(sraw, 0, 128, stream);

    // ---- one-time prep ----
    compute_pos<<<dim3(40), dim3(256), 0, stream>>>(box, posr);
    cvt_bf16<<<dim3(2048), dim3(256), 0, stream>>>(x, x_bf, OUT0 / 4);
    cvt_bf16<<<dim3(2048), dim3(256), 0, stream>>>(W_theta, Wth_bf, 786432);
    cvt_bf16<<<dim3(2048), dim3(256), 0, stream>>>(W_phi, Wph_bf, 786432);
    transpose_cvt<<<dim3(8, 8, 12), dim3(256), 0, stream>>>(
        W_gcn, Wgt, Cc, Cc, (long long)Cc * Cc, (long long)Cc * Cc);
    // GiT[i][d][c] = sum_f Wphi[d][f] * Wtheta[c][f]
    gemm_bf16<2><<<dim3(4, 4, 12), dim3(512), 0, stream>>>(
        Wph_bf, Wth_bf, GiT, Cc, Cc, Cc, Cc, 1,
        262144, 0, 262144, 0, 262144, 0,
        nullptr, nullptr, nullptr, nullptr, nullptr, 0.f, nullptr, 0, 0, nullptr);
    // bias rank-1 terms (exact; zeros for this input)
    uvc_w<<<dim3(128, 12), dim3(256), 0, stream>>>(W_theta, W_phi, b_theta, b_phi, w1w2);
    cvals_k<<<dim3(12), dim3(64), 0, stream>>>(b_theta, b_phi, cvals);
    uvc_x<<<dim3(2560), dim3(256), 0, stream>>>(x, w1w2, u, v);
    // z_all[i][b][c][s] = sum_f Wgt_i[c][f] * x_b[s][f]
    gemm_bf16<2><<<dim3(10, 4, 96), dim3(512), 0, stream>>>(
        Wgt, x_bf, z_all, Cc, Cc, Ss, Cc, 8,
        262144, 0, 0, (long long)SC, (long long)Bb * Cc * Ss, (long long)Cc * Ss,
        nullptr, nullptr, nullptr, nullptr, nullptr, 0.f, nullptr, 0, 0, nullptr);

    const float inv_sqrt = 0.044194173824159216f;  // 1/sqrt(512)

    for (int g = 0; g < 6; ++g) {
        const int i0 = g * 2;
        const int lastg = (g == 5);
        // y pair: ybuf[s][m][c] = x @ G_{i0+s}
        gemm_bf16<2><<<dim3(4, 80, 2), dim3(512), 0, stream>>>(
            x_bf, GiT + (long long)i0 * Cc * Cc, ybuf, Cc, Cc, Cc, Cc, 1,
            0, 0, 262144, 0, (long long)BS * Cc, 0,
            nullptr, nullptr, nullptr, nullptr, nullptr, 0.f, nullptr, 0, 0, nullptr);
        // sim pair = (y @ x^T + u + v + c)*scale, masked
        __bf16* obf = lastg ? (__bf16*)aggF : simbf;
        gemm_bf16<1><<<dim3(10, 10, 16), dim3(512), 0, stream>>>(
            ybuf, x_bf, rel_f32, Cc, Cc, Ss, Cc, 8,
            (long long)BS * Cc, (long long)Ss * Cc, 0, (long long)Ss * Cc,
            0, (long long)Ss * Ss,
            u + (long long)i0 * BS, v + (long long)i0 * BS, cvals + i0,
            posr, OWp, inv_sqrt, obf, (long long)BS * Ss, lastg ? 1 : 2, nullptr);
        // softmax -> relbf pair
        if (!lastg) {
            softmax_rows<1><<<dim3(2 * BS), dim3(256), 0, stream>>>(simbf, nullptr, relbf);
        } else {
            softmax_rows<1><<<dim3(BS), dim3(256), 0, stream>>>(
                (__bf16*)aggF, nullptr, relbf);
            softmax_rows<0><<<dim3(BS), dim3(256), 0, stream>>>(
                nullptr, rel_f32, relbf + (long long)BS * Ss);
        }
        // agg pair = P @ z -> f32 (+ fused LN partial stats)
        gemm_bf16<3><<<dim3(4, 10, 16), dim3(512), 0, stream>>>(
            relbf, z_all + (long long)i0 * Bb * Cc * Ss, aggF,
            Ss, Ss, Cc, Ss, 8,
            (long long)BS * Ss, (long long)Ss * Ss,
            (long long)Bb * Cc * Ss, (long long)Cc * Ss,
            (long long)BS * Cc, (long long)SC,
            nullptr, nullptr, nullptr, nullptr, nullptr, 0.f, nullptr, 0, 0, sraw);
        // finalize pair stats (and reset raw accumulators)
        stats_final<<<dim3(1), dim3(64), 0, stream>>>(sraw, stats);
        // out (+)= relu(LN(agg0)) + relu(LN(agg1))
        ln_relu2<<<dim3(2048), dim3(256), 0, stream>>>(
            aggF, stats, ln_scale + (long long)i0 * SC, ln_bias + (long long)i0 * SC,
            out, g == 0 ? 1 : 0);
    }
}